// Round 15
// baseline (678.925 us; speedup 1.0000x reference)
//
#include <hip/hip_runtime.h>

#define N_NODES 100000
#define N_EDGES 1600000
#define HID 128
#define N_LAYERS 4
#define EPSV 1e-5f
#define NBUCK 1024
#define BSHIFT 7      // 128 nodes per bucket
#define CBLK 4096     // edges per scatter block
#define NREP 8        // deg_out replicas (one per XCD)
#define LSTR 40       // LDS row stride in shorts (80B: 16B-aligned, 2-way-max bank conflicts = free)

using f32x4 = __attribute__((ext_vector_type(4))) float;
using s16x8 = __attribute__((ext_vector_type(8))) short;

__device__ __forceinline__ unsigned short f2bf(float f) {
  union { float f; unsigned u; } c{f};
  unsigned u = c.u;
  return (unsigned short)((u + 0x7fffu + ((u >> 16) & 1u)) >> 16);
}
__device__ __forceinline__ float bf2f(unsigned short s) {
  union { unsigned u; float f; } c{(unsigned)s << 16};
  return c.f;
}

// ---------------- Pass A: bucket histogram (LDS) + replicated deg_out (high-TLP) ----------------
__global__ __launch_bounds__(256) void k_hist(const int* __restrict__ src, const int* __restrict__ dst,
                                              int* __restrict__ bucket_cnt, int* __restrict__ deg_out_r) {
  __shared__ int h[NBUCK];
  for (int i = threadIdx.x; i < NBUCK; i += 256) h[i] = 0;
  __syncthreads();
  int* deg_my = deg_out_r + (size_t)(blockIdx.x & (NREP - 1)) * N_NODES;
  int per = (N_EDGES + gridDim.x - 1) / gridDim.x;
  int lo = blockIdx.x * per;
  int hi = lo + per; if (hi > N_EDGES) hi = N_EDGES;
  for (int i = lo + threadIdx.x; i < hi; i += 256) {
    atomicAdd(&h[dst[i] >> BSHIFT], 1);
    atomicAdd(&deg_my[src[i]], 1);  // XCD-local replica + high occupancy to hide latency
  }
  __syncthreads();
  for (int i = threadIdx.x; i < NBUCK; i += 256)
    if (h[i]) atomicAdd(&bucket_cnt[i], h[i]);
}

// ---------------- Pass B: scan 1024 bucket counts; zero bucket_fill ----------------
__global__ __launch_bounds__(256) void k_bscan(const int* __restrict__ cnt, int* __restrict__ base,
                                               int* __restrict__ fill) {
  __shared__ int wsum[4];
  int tid = threadIdx.x;
  int4 v = *(const int4*)(cnt + tid * 4);
  int s4 = v.x + v.y + v.z + v.w;
  int lane = tid & 63, wid = tid >> 6;
  int sc = s4;
#pragma unroll
  for (int off = 1; off < 64; off <<= 1) {
    int u = __shfl_up(sc, off, 64);
    if (lane >= off) sc += u;
  }
  if (lane == 63) wsum[wid] = sc;
  __syncthreads();
  int woff = 0;
#pragma unroll
  for (int w = 0; w < 4; ++w) woff += (w < wid) ? wsum[w] : 0;
  int excl = woff + sc - s4;
  int4 o;
  o.x = excl; o.y = o.x + v.x; o.z = o.y + v.y; o.w = o.z + v.z;
  *(int4*)(base + tid * 4) = o;
  *(int4*)(fill + tid * 4) = make_int4(0, 0, 0, 0);
  if (tid == 255) base[NBUCK] = woff + sc;  // == N_EDGES
}

// ---------------- Pass C: block-local staged scatter (no atomics beyond cursors) ----------------
__global__ __launch_bounds__(256) void k_scatter2(const int* __restrict__ src, const int* __restrict__ dst,
                                                  const int* __restrict__ bucket_base, int* __restrict__ bucket_fill,
                                                  int2* __restrict__ pairs) {
  __shared__ int hist[NBUCK];
  __shared__ int loff[NBUCK];
  __shared__ int gbase_s[NBUCK];
  __shared__ int lcur[NBUCK];
  __shared__ int wsum[4];
  __shared__ int2 stage[CBLK];                 // 32 KB
  __shared__ unsigned short sbuck[CBLK];       // 8 KB
  int tid = threadIdx.x;
  int e0 = blockIdx.x * CBLK;
  int e1 = e0 + CBLK; if (e1 > N_EDGES) e1 = N_EDGES;
  int n = e1 - e0;
  for (int i = tid; i < NBUCK; i += 256) hist[i] = 0;
  __syncthreads();
  int2 ev[CBLK / 256];
  int nb[CBLK / 256];
#pragma unroll
  for (int j = 0; j < CBLK / 256; ++j) {
    int idx = e0 + j * 256 + tid;
    nb[j] = -1;
    if (idx < e1) {
      ev[j] = make_int2(src[idx], dst[idx]);
      nb[j] = ev[j].y >> BSHIFT;
      atomicAdd(&hist[nb[j]], 1);
    }
  }
  __syncthreads();
  int4 hv = *(const int4*)(hist + tid * 4);
  int s4 = hv.x + hv.y + hv.z + hv.w;
  int lane = tid & 63, wid = tid >> 6;
  int sc = s4;
#pragma unroll
  for (int off = 1; off < 64; off <<= 1) {
    int u = __shfl_up(sc, off, 64);
    if (lane >= off) sc += u;
  }
  if (lane == 63) wsum[wid] = sc;
  __syncthreads();
  int woff = 0;
#pragma unroll
  for (int w = 0; w < 4; ++w) woff += (w < wid) ? wsum[w] : 0;
  int excl = woff + sc - s4;
  loff[tid * 4 + 0] = excl;
  loff[tid * 4 + 1] = excl + hv.x;
  loff[tid * 4 + 2] = excl + hv.x + hv.y;
  loff[tid * 4 + 3] = excl + hv.x + hv.y + hv.z;
  __syncthreads();
  for (int b = tid; b < NBUCK; b += 256) {
    int c = hist[b];
    if (c > 0) gbase_s[b] = bucket_base[b] + atomicAdd(&bucket_fill[b], c);
    lcur[b] = loff[b];
  }
  __syncthreads();
#pragma unroll
  for (int j = 0; j < CBLK / 256; ++j) {
    if (nb[j] >= 0) {
      int p = atomicAdd(&lcur[nb[j]], 1);
      stage[p] = ev[j];
      sbuck[p] = (unsigned short)nb[j];
    }
  }
  __syncthreads();
  for (int s = tid; s < n; s += 256) {
    int b = sbuck[s];
    pairs[gbase_s[b] + (s - loff[b])] = stage[s];
  }
}

// ---------------- Pass D: per-bucket exact CSR (no global atomics) ----------------
__global__ __launch_bounds__(256) void k_bucket_csr(const int2* __restrict__ pairs, const int* __restrict__ base,
                                                    int* __restrict__ row_ptr, float* __restrict__ norm_dst,
                                                    int* __restrict__ csr_src) {
  __shared__ int hist[128];
  __shared__ int excl[129];
  __shared__ int curs[128];
  int bk = blockIdx.x;
  int b0 = base[bk], b1 = base[bk + 1];
  int tid = threadIdx.x;
  if (tid < 128) hist[tid] = 0;
  __syncthreads();
  for (int i = b0 + tid; i < b1; i += 256) atomicAdd(&hist[pairs[i].y & 127], 1);
  __syncthreads();
  if (tid < 128) {
    int v = hist[tid];
    int lane = tid & 63;
    int sc = v;
#pragma unroll
    for (int off = 1; off < 64; off <<= 1) {
      int u = __shfl_up(sc, off, 64);
      if (lane >= off) sc += u;
    }
    excl[tid] = sc - v;
    if (lane == 63 && tid < 64) excl[128] = sc;
  }
  __syncthreads();
  if (tid >= 64 && tid < 128) excl[tid] += excl[128];
  __syncthreads();
  int gbase = bk << BSHIFT;
  if (tid < 128) {
    int g = gbase + tid;
    if (g < N_NODES) {
      row_ptr[g] = b0 + excl[tid];
      norm_dst[g] = hist[tid] > 0 ? rsqrtf((float)hist[tid]) : 0.f;
    } else if (g == N_NODES) {
      row_ptr[N_NODES] = b0 + excl[tid];
    }
    curs[tid] = excl[tid];
  }
  __syncthreads();
  for (int i = b0 + tid; i < b1; i += 256) {
    int2 p = pairs[i];
    int pos = b0 + atomicAdd(&curs[p.y & 127], 1);
    csr_src[pos] = p.x;
  }
}

// ---------------- norm_src from replicated deg_out ----------------
__global__ __launch_bounds__(256) void k_norms_src(const int* __restrict__ deg_out_r, float* __restrict__ norm_src) {
  int i = blockIdx.x * 256 + threadIdx.x;
  if (i < N_NODES) {
    int d = 0;
#pragma unroll
    for (int r = 0; r < NREP; ++r) d += deg_out_r[(size_t)r * N_NODES + i];
    norm_src[i] = d > 0 ? rsqrtf((float)d) : 0.f;
  }
}

// ---------------- embedding lookup: writes x (fp32) + xb (bf16, prescaled by norm_src) ----------------
__global__ __launch_bounds__(256) void k_embed(const int* __restrict__ h, const float* __restrict__ emb,
                                               const float* __restrict__ norm_src,
                                               float* __restrict__ x, unsigned short* __restrict__ xb) {
  int i = blockIdx.x * 256 + threadIdx.x;  // over N*32 float4
  const int total = N_NODES * (HID / 4);
  if (i < total) {
    int r = i >> 5, c = i & 31;
    float4 v = ((const float4*)emb)[h[r] * (HID / 4) + c];
    ((float4*)x)[i] = v;
    float ns = norm_src[r];
    uint2 p;
    p.x = (unsigned)f2bf(v.x * ns) | ((unsigned)f2bf(v.y * ns) << 16);
    p.y = (unsigned)f2bf(v.z * ns) | ((unsigned)f2bf(v.w * ns) << 16);
    *(uint2*)(xb + (size_t)i * 4) = p;
  }
}

// ---------------- W split+transpose: Wt[l][col][k] hi/lo bf16 (GCN layers) ----------------
__global__ __launch_bounds__(128) void k_wsplit(const float* __restrict__ W, unsigned short* __restrict__ Wh,
                                                unsigned short* __restrict__ Wl) {
  int l = blockIdx.x >> 7, k = blockIdx.x & 127;
  int c = threadIdx.x;
  float w = W[(size_t)l * HID * HID + k * HID + c];
  unsigned short h = f2bf(w);
  Wh[(size_t)l * HID * HID + c * HID + k] = h;
  Wl[(size_t)l * HID * HID + c * HID + k] = f2bf(w - bf2f(h));
}

// ---------------- generic W split+transpose for MLP weights: [K][C] -> hi/lo [C][K] ----------------
__global__ __launch_bounds__(256) void k_wsplit_t(const float* __restrict__ Win,
                                                  unsigned short* __restrict__ Wth,
                                                  unsigned short* __restrict__ Wtl, int K, int C) {
  int idx = blockIdx.x * 256 + threadIdx.x;
  if (idx < K * C) {
    int k = idx / C, c = idx - k * C;
    float w = Win[idx];
    unsigned short h = f2bf(w);
    Wth[(size_t)c * K + k] = h;
    Wtl[(size_t)c * K + k] = f2bf(w - bf2f(h));
  }
}

// ---------------- aggregation (prescaled bf16 gather, fp32 accumulate, hi/lo bf16 output) ----------------
__global__ __launch_bounds__(256) void k_agg(const unsigned short* __restrict__ xb, const int* __restrict__ row_ptr,
                                             const int* __restrict__ csr_src, const float* __restrict__ norm_dst,
                                             unsigned short* __restrict__ agg_hi, unsigned short* __restrict__ agg_lo) {
  int node = blockIdx.x * 16 + (threadIdx.x >> 4);
  int l16 = threadIdx.x & 15;
  if (node >= N_NODES) return;
  int s0 = row_ptr[node], s1 = row_ptr[node + 1];
  float acc[8];
#pragma unroll
  for (int j = 0; j < 8; ++j) acc[j] = 0.f;
  int i = s0;
  for (; i + 7 < s1; i += 8) {
    uint4 u[8];
#pragma unroll
    for (int e = 0; e < 8; ++e)
      u[e] = *(const uint4*)(xb + (size_t)csr_src[i + e] * HID + l16 * 8);
#pragma unroll
    for (int e = 0; e < 8; ++e) {
      unsigned uu[4] = {u[e].x, u[e].y, u[e].z, u[e].w};
#pragma unroll
      for (int q = 0; q < 4; ++q) {
        union { unsigned u; float f; } lo{uu[q] << 16}, hi{uu[q] & 0xffff0000u};
        acc[q * 2 + 0] += lo.f;
        acc[q * 2 + 1] += hi.f;
      }
    }
  }
  for (; i + 3 < s1; i += 4) {
    uint4 u[4];
#pragma unroll
    for (int e = 0; e < 4; ++e)
      u[e] = *(const uint4*)(xb + (size_t)csr_src[i + e] * HID + l16 * 8);
#pragma unroll
    for (int e = 0; e < 4; ++e) {
      unsigned uu[4] = {u[e].x, u[e].y, u[e].z, u[e].w};
#pragma unroll
      for (int q = 0; q < 4; ++q) {
        union { unsigned u; float f; } lo{uu[q] << 16}, hi{uu[q] & 0xffff0000u};
        acc[q * 2 + 0] += lo.f;
        acc[q * 2 + 1] += hi.f;
      }
    }
  }
  for (; i < s1; ++i) {
    uint4 u = *(const uint4*)(xb + (size_t)csr_src[i] * HID + l16 * 8);
    unsigned uu[4] = {u.x, u.y, u.z, u.w};
#pragma unroll
    for (int q = 0; q < 4; ++q) {
      union { unsigned u; float f; } lo{uu[q] << 16}, hi{uu[q] & 0xffff0000u};
      acc[q * 2 + 0] += lo.f;
      acc[q * 2 + 1] += hi.f;
    }
  }
  float nd = norm_dst[node];
  unsigned short hh[8], ll[8];
#pragma unroll
  for (int j = 0; j < 8; ++j) {
    float v = acc[j] * nd;
    hh[j] = f2bf(v);
    ll[j] = f2bf(v - bf2f(hh[j]));
  }
  uint4 ho, lo4;
  ho.x = (unsigned)hh[0] | ((unsigned)hh[1] << 16); ho.y = (unsigned)hh[2] | ((unsigned)hh[3] << 16);
  ho.z = (unsigned)hh[4] | ((unsigned)hh[5] << 16); ho.w = (unsigned)hh[6] | ((unsigned)hh[7] << 16);
  lo4.x = (unsigned)ll[0] | ((unsigned)ll[1] << 16); lo4.y = (unsigned)ll[2] | ((unsigned)ll[3] << 16);
  lo4.z = (unsigned)ll[4] | ((unsigned)ll[5] << 16); lo4.w = (unsigned)ll[6] | ((unsigned)ll[7] << 16);
  *(uint4*)(agg_hi + (size_t)node * HID + l16 * 8) = ho;
  *(uint4*)(agg_lo + (size_t)node * HID + l16 * 8) = lo4;
}

// ---------------- MFMA GEMM: Y = A@W + b, bf16x3 (fp32-grade), fused BN stats; Yb output bf16 ----------------
__global__ __launch_bounds__(256, 4) void k_gemm_mfma(const unsigned short* __restrict__ Ah,
                                                      const unsigned short* __restrict__ Al,
                                                      const unsigned short* __restrict__ Bh,
                                                      const unsigned short* __restrict__ Bl,
                                                      const float* __restrict__ bias,
                                                      unsigned short* __restrict__ Y16,
                                                      float* __restrict__ sums, float* __restrict__ sumsq) {
  __shared__ unsigned short sAh[128 * LSTR], sAl[128 * LSTR], sBh[128 * LSTR], sBl[128 * LSTR];  // 40960 B
  const int tid = threadIdx.x;
  const int lane = tid & 63, wid = tid >> 6;
  const int l15 = lane & 15, kg = lane >> 4;
  const int row0 = blockIdx.x * 128;

  f32x4 acc[2][8];
#pragma unroll
  for (int mi = 0; mi < 2; ++mi)
#pragma unroll
    for (int ni = 0; ni < 8; ++ni) acc[mi][ni] = (f32x4){0.f, 0.f, 0.f, 0.f};

  for (int kb = 0; kb < 4; ++kb) {
    const int k0 = kb * 32;
#pragma unroll
    for (int it = 0; it < 2; ++it) {
      int idx = tid * 2 + it;
      int r = idx >> 2, q = idx & 3;
      int gr = row0 + r;
      s16x8 vh = {0, 0, 0, 0, 0, 0, 0, 0}, vl = {0, 0, 0, 0, 0, 0, 0, 0};
      if (gr < N_NODES) {
        vh = *(const s16x8*)(Ah + (size_t)gr * HID + k0 + q * 8);
        vl = *(const s16x8*)(Al + (size_t)gr * HID + k0 + q * 8);
      }
      *(s16x8*)&sAh[r * LSTR + q * 8] = vh;
      *(s16x8*)&sAl[r * LSTR + q * 8] = vl;
      *(s16x8*)&sBh[r * LSTR + q * 8] = *(const s16x8*)(Bh + (size_t)r * HID + k0 + q * 8);
      *(s16x8*)&sBl[r * LSTR + q * 8] = *(const s16x8*)(Bl + (size_t)r * HID + k0 + q * 8);
    }
    __syncthreads();
    s16x8 afh[2], afl[2];
#pragma unroll
    for (int mi = 0; mi < 2; ++mi) {
      int ar = wid * 32 + mi * 16 + l15;
      afh[mi] = *(const s16x8*)&sAh[ar * LSTR + kg * 8];
      afl[mi] = *(const s16x8*)&sAl[ar * LSTR + kg * 8];
    }
#pragma unroll
    for (int ni = 0; ni < 8; ++ni) {
      int bc = ni * 16 + l15;
      s16x8 bh = *(const s16x8*)&sBh[bc * LSTR + kg * 8];
      s16x8 bl = *(const s16x8*)&sBl[bc * LSTR + kg * 8];
#pragma unroll
      for (int mi = 0; mi < 2; ++mi) {
        acc[mi][ni] = __builtin_amdgcn_mfma_f32_16x16x32_bf16(afh[mi], bh, acc[mi][ni], 0, 0, 0);
        acc[mi][ni] = __builtin_amdgcn_mfma_f32_16x16x32_bf16(afh[mi], bl, acc[mi][ni], 0, 0, 0);
        acc[mi][ni] = __builtin_amdgcn_mfma_f32_16x16x32_bf16(afl[mi], bh, acc[mi][ni], 0, 0, 0);
      }
    }
    __syncthreads();
  }

  float bv[8], sp[8], qp[8];
#pragma unroll
  for (int ni = 0; ni < 8; ++ni) {
    bv[ni] = bias[ni * 16 + l15];
    sp[ni] = 0.f; qp[ni] = 0.f;
  }
#pragma unroll
  for (int mi = 0; mi < 2; ++mi) {
    int rbase = row0 + wid * 32 + mi * 16 + kg * 4;
#pragma unroll
    for (int reg = 0; reg < 4; ++reg) {
      int r = rbase + reg;
      if (r < N_NODES) {
        unsigned short* yr = Y16 + (size_t)r * HID;
#pragma unroll
        for (int ni = 0; ni < 8; ++ni) {
          float y = acc[mi][ni][reg] + bv[ni];
          yr[ni * 16 + l15] = f2bf(y);
          sp[ni] += y;
          qp[ni] += y * y;
        }
      }
    }
  }
  __syncthreads();
  float* red_s = (float*)sAh;  // [16][128] = 8KB
  float* red_q = (float*)sBh;
  int slot = wid * 4 + kg;
#pragma unroll
  for (int ni = 0; ni < 8; ++ni) {
    red_s[slot * 128 + ni * 16 + l15] = sp[ni];
    red_q[slot * 128 + ni * 16 + l15] = qp[ni];
  }
  __syncthreads();
  if (tid < 128) {
    float a = 0.f, b2 = 0.f;
#pragma unroll
    for (int s = 0; s < 16; ++s) {
      a += red_s[s * 128 + tid];
      b2 += red_q[s * 128 + tid];
    }
    atomicAdd(&sums[tid], a);
    atomicAdd(&sumsq[tid], b2);
  }
}

// ---------------- BN finalize ----------------
__global__ __launch_bounds__(128) void k_bn_final(const float* __restrict__ sums, const float* __restrict__ sumsq,
                                                  const float* __restrict__ gamma, const float* __restrict__ beta,
                                                  float* __restrict__ scale, float* __restrict__ shift) {
  int d = threadIdx.x;
  float mu = sums[d] / (float)N_NODES;
  float var = sumsq[d] / (float)N_NODES - mu * mu;
  float sc = gamma[d] * rsqrtf(var + EPSV);
  scale[d] = sc;
  shift[d] = beta[d] - mu * sc;
}

// ---------------- BN apply + relu + residual; Yb bf16 in; writes x (fp32) + xb (bf16, prescaled) ----------------
__global__ __launch_bounds__(256) void k_bn_apply(const unsigned short* __restrict__ Y16,
                                                  const float* __restrict__ scale,
                                                  const float* __restrict__ shift, const float* __restrict__ norm_src,
                                                  float* __restrict__ x, unsigned short* __restrict__ xb) {
  int i = blockIdx.x * 256 + threadIdx.x;  // over N*16 chunks of 8 cols
  const int total = N_NODES * (HID / 8);
  if (i >= total) return;
  int c8 = i & 15, r = i >> 4;
  uint4 yu = *(const uint4*)(Y16 + (size_t)r * HID + c8 * 8);
  unsigned yw[4] = {yu.x, yu.y, yu.z, yu.w};
  float y[8];
#pragma unroll
  for (int q = 0; q < 4; ++q) {
    union { unsigned u; float f; } lo{yw[q] << 16}, hi{yw[q] & 0xffff0000u};
    y[q * 2 + 0] = lo.f;
    y[q * 2 + 1] = hi.f;
  }
  float4 sc0 = *(const float4*)(scale + c8 * 8);
  float4 sc1 = *(const float4*)(scale + c8 * 8 + 4);
  float4 sh0 = *(const float4*)(shift + c8 * 8);
  float4 sh1 = *(const float4*)(shift + c8 * 8 + 4);
  float scv[8] = {sc0.x, sc0.y, sc0.z, sc0.w, sc1.x, sc1.y, sc1.z, sc1.w};
  float shv[8] = {sh0.x, sh0.y, sh0.z, sh0.w, sh1.x, sh1.y, sh1.z, sh1.w};
  float* xr = x + (size_t)r * HID + c8 * 8;
  float4 x0 = *(const float4*)xr;
  float4 x1 = *(const float4*)(xr + 4);
  float xv[8] = {x0.x, x0.y, x0.z, x0.w, x1.x, x1.y, x1.z, x1.w};
  float o[8];
#pragma unroll
  for (int q = 0; q < 8; ++q) o[q] = fmaxf(y[q] * scv[q] + shv[q], 0.f) + xv[q];
  *(float4*)xr = make_float4(o[0], o[1], o[2], o[3]);
  *(float4*)(xr + 4) = make_float4(o[4], o[5], o[6], o[7]);
  float ns = norm_src[r];
  uint4 p;
  p.x = (unsigned)f2bf(o[0] * ns) | ((unsigned)f2bf(o[1] * ns) << 16);
  p.y = (unsigned)f2bf(o[2] * ns) | ((unsigned)f2bf(o[3] * ns) << 16);
  p.z = (unsigned)f2bf(o[4] * ns) | ((unsigned)f2bf(o[5] * ns) << 16);
  p.w = (unsigned)f2bf(o[6] * ns) | ((unsigned)f2bf(o[7] * ns) << 16);
  *(uint4*)(xb + (size_t)r * HID + c8 * 8) = p;
}

// ---------------- MFMA readout: BN(l=3) + residual -> 128->64->32->6 (Yb bf16 in) ----------------
__global__ __launch_bounds__(256, 4) void k_readout(const unsigned short* __restrict__ Y16,
                                                    const float* __restrict__ Xres,
                                                    const float* __restrict__ scale, const float* __restrict__ shift,
                                                    const unsigned short* __restrict__ B1h, const unsigned short* __restrict__ B1l,
                                                    const float* __restrict__ b1,
                                                    const unsigned short* __restrict__ B2h, const unsigned short* __restrict__ B2l,
                                                    const float* __restrict__ b2,
                                                    const float* __restrict__ W3, const float* __restrict__ b3,
                                                    float* __restrict__ out) {
  __shared__ unsigned short sAh[128 * 72], sAl[128 * 72];  // 36864 B
  __shared__ float scs[128], shs[128];
  __shared__ float Ws3s[192];
  const int tid = threadIdx.x;
  const int lane = tid & 63, wid = tid >> 6;
  const int l15 = lane & 15, kg = lane >> 4;
  const int row0 = blockIdx.x * 128;
  if (tid < 128) { scs[tid] = scale[tid]; shs[tid] = shift[tid]; }
  if (tid < 192) Ws3s[tid] = W3[tid];
  __syncthreads();

  f32x4 acc1[2][4];
#pragma unroll
  for (int mi = 0; mi < 2; ++mi)
#pragma unroll
    for (int ni = 0; ni < 4; ++ni) acc1[mi][ni] = (f32x4){0.f, 0.f, 0.f, 0.f};

  // ---- layer 1: two K-slabs of 64 ----
  for (int slab = 0; slab < 2; ++slab) {
    const int c0 = slab * 64;
#pragma unroll
    for (int it = 0; it < 4; ++it) {
      int idx = tid + it * 256;        // 0..1023
      int r = idx >> 3, q = idx & 7;   // row, 8-col chunk
      int gr = row0 + r;
      float v[8];
      if (gr < N_NODES) {
        uint4 yu = *(const uint4*)(Y16 + (size_t)gr * HID + c0 + q * 8);
        unsigned yw[4] = {yu.x, yu.y, yu.z, yu.w};
        const float* xp = Xres + (size_t)gr * HID + c0 + q * 8;
        float4 x0 = *(const float4*)xp, x1 = *(const float4*)(xp + 4);
        float xvv[8] = {x0.x, x0.y, x0.z, x0.w, x1.x, x1.y, x1.z, x1.w};
        const float* scp = &scs[c0 + q * 8];
        const float* shp = &shs[c0 + q * 8];
#pragma unroll
        for (int qq = 0; qq < 4; ++qq) {
          union { unsigned u; float f; } lo{yw[qq] << 16}, hi{yw[qq] & 0xffff0000u};
          v[qq * 2 + 0] = fmaxf(lo.f * scp[qq * 2 + 0] + shp[qq * 2 + 0], 0.f) + xvv[qq * 2 + 0];
          v[qq * 2 + 1] = fmaxf(hi.f * scp[qq * 2 + 1] + shp[qq * 2 + 1], 0.f) + xvv[qq * 2 + 1];
        }
      } else {
#pragma unroll
        for (int j = 0; j < 8; ++j) v[j] = 0.f;
      }
      short hh[8], ll[8];
#pragma unroll
      for (int j = 0; j < 8; ++j) {
        unsigned short hb = f2bf(v[j]);
        hh[j] = (short)hb;
        ll[j] = (short)f2bf(v[j] - bf2f(hb));
      }
      *(s16x8*)&sAh[r * 72 + q * 8] = (s16x8){hh[0], hh[1], hh[2], hh[3], hh[4], hh[5], hh[6], hh[7]};
      *(s16x8*)&sAl[r * 72 + q * 8] = (s16x8){ll[0], ll[1], ll[2], ll[3], ll[4], ll[5], ll[6], ll[7]};
    }
    __syncthreads();
#pragma unroll
    for (int kb = 0; kb < 2; ++kb) {
      s16x8 afh[2], afl[2];
#pragma unroll
      for (int mi = 0; mi < 2; ++mi) {
        int ar = wid * 32 + mi * 16 + l15;
        afh[mi] = *(const s16x8*)&sAh[ar * 72 + kb * 32 + kg * 8];
        afl[mi] = *(const s16x8*)&sAl[ar * 72 + kb * 32 + kg * 8];
      }
#pragma unroll
      for (int ni = 0; ni < 4; ++ni) {
        int bc = ni * 16 + l15;
        s16x8 bh = *(const s16x8*)(B1h + (size_t)bc * 128 + c0 + kb * 32 + kg * 8);
        s16x8 bl = *(const s16x8*)(B1l + (size_t)bc * 128 + c0 + kb * 32 + kg * 8);
#pragma unroll
        for (int mi = 0; mi < 2; ++mi) {
          acc1[mi][ni] = __builtin_amdgcn_mfma_f32_16x16x32_bf16(afh[mi], bh, acc1[mi][ni], 0, 0, 0);
          acc1[mi][ni] = __builtin_amdgcn_mfma_f32_16x16x32_bf16(afh[mi], bl, acc1[mi][ni], 0, 0, 0);
          acc1[mi][ni] = __builtin_amdgcn_mfma_f32_16x16x32_bf16(afl[mi], bh, acc1[mi][ni], 0, 0, 0);
        }
      }
    }
    __syncthreads();
  }

  // ---- h1 = relu(acc1 + b1) -> LDS hi/lo ----
  float bv1[4];
#pragma unroll
  for (int ni = 0; ni < 4; ++ni) bv1[ni] = b1[ni * 16 + l15];
#pragma unroll
  for (int mi = 0; mi < 2; ++mi)
#pragma unroll
    for (int ni = 0; ni < 4; ++ni)
#pragma unroll
      for (int reg = 0; reg < 4; ++reg) {
        int rr = wid * 32 + mi * 16 + kg * 4 + reg;
        float v = fmaxf(acc1[mi][ni][reg] + bv1[ni], 0.f);
        unsigned short hb = f2bf(v);
        sAh[rr * 72 + ni * 16 + l15] = hb;
        sAl[rr * 72 + ni * 16 + l15] = f2bf(v - bf2f(hb));
      }
  __syncthreads();

  // ---- layer 2 via MFMA, K=64 ----
  f32x4 acc2[2][2];
#pragma unroll
  for (int mi = 0; mi < 2; ++mi)
#pragma unroll
    for (int ni = 0; ni < 2; ++ni) acc2[mi][ni] = (f32x4){0.f, 0.f, 0.f, 0.f};
#pragma unroll
  for (int kb = 0; kb < 2; ++kb) {
    s16x8 afh[2], afl[2];
#pragma unroll
    for (int mi = 0; mi < 2; ++mi) {
      int ar = wid * 32 + mi * 16 + l15;
      afh[mi] = *(const s16x8*)&sAh[ar * 72 + kb * 32 + kg * 8];
      afl[mi] = *(const s16x8*)&sAl[ar * 72 + kb * 32 + kg * 8];
    }
#pragma unroll
    for (int ni = 0; ni < 2; ++ni) {
      int bc = ni * 16 + l15;
      s16x8 bh = *(const s16x8*)(B2h + (size_t)bc * 64 + kb * 32 + kg * 8);
      s16x8 bl = *(const s16x8*)(B2l + (size_t)bc * 64 + kb * 32 + kg * 8);
#pragma unroll
      for (int mi = 0; mi < 2; ++mi) {
        acc2[mi][ni] = __builtin_amdgcn_mfma_f32_16x16x32_bf16(afh[mi], bh, acc2[mi][ni], 0, 0, 0);
        acc2[mi][ni] = __builtin_amdgcn_mfma_f32_16x16x32_bf16(afh[mi], bl, acc2[mi][ni], 0, 0, 0);
        acc2[mi][ni] = __builtin_amdgcn_mfma_f32_16x16x32_bf16(afl[mi], bh, acc2[mi][ni], 0, 0, 0);
      }
    }
  }
  __syncthreads();

  // ---- h2 = relu(acc2 + b2) -> LDS fp32 [128][36] ----
  float* h2s = (float*)sAh;
  float bv2[2];
#pragma unroll
  for (int ni = 0; ni < 2; ++ni) bv2[ni] = b2[ni * 16 + l15];
#pragma unroll
  for (int mi = 0; mi < 2; ++mi)
#pragma unroll
    for (int ni = 0; ni < 2; ++ni)
#pragma unroll
      for (int reg = 0; reg < 4; ++reg) {
        int rr = wid * 32 + mi * 16 + kg * 4 + reg;
        h2s[rr * 36 + ni * 16 + l15] = fmaxf(acc2[mi][ni][reg] + bv2[ni], 0.f);
      }
  __syncthreads();

  // ---- layer 3: per-thread ----
  if (tid < 128) {
    int gr = row0 + tid;
    if (gr < N_NODES) {
      float h2r[32];
#pragma unroll
      for (int q = 0; q < 8; ++q) {
        float4 t = *(const float4*)&h2s[tid * 36 + q * 4];
        h2r[q * 4 + 0] = t.x; h2r[q * 4 + 1] = t.y; h2r[q * 4 + 2] = t.z; h2r[q * 4 + 3] = t.w;
      }
      float p[6];
#pragma unroll
      for (int o = 0; o < 6; ++o) p[o] = b3[o];
#pragma unroll
      for (int k = 0; k < 32; ++k)
#pragma unroll
        for (int o = 0; o < 6; ++o) p[o] += h2r[k] * Ws3s[k * 6 + o];
      float* orow = out + (size_t)gr * 6;
#pragma unroll
      for (int o = 0; o < 6; ++o) orow[o] = p[o];
    }
  }
}

extern "C" void kernel_launch(void* const* d_in, const int* in_sizes, int n_in,
                              void* d_out, int out_size, void* d_ws, size_t ws_size,
                              hipStream_t stream) {
  const int* h = (const int*)d_in[0];
  const int* src = (const int*)d_in[1];
  const int* dst = (const int*)d_in[2];
  const float* emb = (const float*)d_in[3];
  const float* W = (const float*)d_in[4];
  const float* b = (const float*)d_in[5];
  const float* gamma = (const float*)d_in[6];
  const float* beta = (const float*)d_in[7];
  const float* W1 = (const float*)d_in[8];
  const float* b1 = (const float*)d_in[9];
  const float* W2 = (const float*)d_in[10];
  const float* b2 = (const float*)d_in[11];
  const float* W3 = (const float*)d_in[12];
  const float* b3 = (const float*)d_in[13];
  float* out = (float*)d_out;

  char* ws = (char*)d_ws;
  size_t off = 0;
  auto alloc = [&](size_t bytes) -> void* {
    void* p = ws + off;
    off += (bytes + 255) & ~(size_t)255;
    return p;
  };
  int* deg_out_r = (int*)alloc((size_t)NREP * N_NODES * 4);
  float* norm_src = (float*)alloc(N_NODES * 4);
  float* norm_dst = (float*)alloc(N_NODES * 4);
  int* row_ptr = (int*)alloc((N_NODES + 1) * 4);
  int* csr_src = (int*)alloc((size_t)N_EDGES * 4);
  int* bucket_cnt = (int*)alloc(NBUCK * 4);
  int* bucket_base = (int*)alloc((NBUCK + 1) * 4);
  int* bucket_fill = (int*)alloc(NBUCK * 4);
  float* x = (float*)alloc((size_t)N_NODES * HID * 4);
  unsigned short* xb = (unsigned short*)alloc((size_t)N_NODES * HID * 2);
  unsigned short* agg_hi = (unsigned short*)alloc((size_t)N_NODES * HID * 2);
  unsigned short* agg_lo = (unsigned short*)alloc((size_t)N_NODES * HID * 2);
  unsigned short* Yb16 = (unsigned short*)alloc((size_t)N_NODES * HID * 2);
  unsigned short* Wh = (unsigned short*)alloc((size_t)N_LAYERS * HID * HID * 2);
  unsigned short* Wl = (unsigned short*)alloc((size_t)N_LAYERS * HID * HID * 2);
  unsigned short* B1h = (unsigned short*)alloc(64 * 128 * 2);
  unsigned short* B1l = (unsigned short*)alloc(64 * 128 * 2);
  unsigned short* B2h = (unsigned short*)alloc(32 * 64 * 2);
  unsigned short* B2l = (unsigned short*)alloc(32 * 64 * 2);
  float* sums = (float*)alloc(512);
  float* sumsq = (float*)alloc(512);
  float* scale = (float*)alloc(512);
  float* shift = (float*)alloc(512);
  int2* pairs = (int2*)alloc((size_t)N_EDGES * 8);  // 12.8MB dedicated

  hipMemsetAsync(deg_out_r, 0, (size_t)NREP * N_NODES * 4, stream);
  hipMemsetAsync(bucket_cnt, 0, NBUCK * 4, stream);
  k_hist<<<1024, 256, 0, stream>>>(src, dst, bucket_cnt, deg_out_r);
  k_bscan<<<1, 256, 0, stream>>>(bucket_cnt, bucket_base, bucket_fill);
  k_scatter2<<<(N_EDGES + CBLK - 1) / CBLK, 256, 0, stream>>>(src, dst, bucket_base, bucket_fill, pairs);
  k_bucket_csr<<<NBUCK, 256, 0, stream>>>(pairs, bucket_base, row_ptr, norm_dst, csr_src);
  k_norms_src<<<(N_NODES + 255) / 256, 256, 0, stream>>>(deg_out_r, norm_src);
  k_embed<<<(N_NODES * (HID / 4) + 255) / 256, 256, 0, stream>>>(h, emb, norm_src, x, xb);
  k_wsplit<<<N_LAYERS * 128, 128, 0, stream>>>(W, Wh, Wl);
  k_wsplit_t<<<(128 * 64 + 255) / 256, 256, 0, stream>>>(W1, B1h, B1l, 128, 64);
  k_wsplit_t<<<(64 * 32 + 255) / 256, 256, 0, stream>>>(W2, B2h, B2l, 64, 32);

  for (int l = 0; l < N_LAYERS; ++l) {
    k_agg<<<(N_NODES + 15) / 16, 256, 0, stream>>>(xb, row_ptr, csr_src, norm_dst, agg_hi, agg_lo);
    hipMemsetAsync(sums, 0, 1024, stream);  // sums+sumsq contiguous
    k_gemm_mfma<<<(N_NODES + 127) / 128, 256, 0, stream>>>(agg_hi, agg_lo,
                                                           Wh + (size_t)l * HID * HID, Wl + (size_t)l * HID * HID,
                                                           b + l * HID, Yb16, sums, sumsq);
    k_bn_final<<<1, 128, 0, stream>>>(sums, sumsq, gamma + l * HID, beta + l * HID, scale, shift);
    if (l < N_LAYERS - 1) {
      k_bn_apply<<<(N_NODES * (HID / 8) + 255) / 256, 256, 0, stream>>>(Yb16, scale, shift, norm_src, x, xb);
    }
  }
  k_readout<<<(N_NODES + 127) / 128, 256, 0, stream>>>(Yb16, x, scale, shift,
                                                       B1h, B1l, b1, B2h, B2l, b2, W3, b3, out);
}

// Round 16
// 647.137 us; speedup vs baseline: 1.0491x; 1.0491x over previous
//
#include <hip/hip_runtime.h>

#define N_NODES 100000
#define N_EDGES 1600000
#define HID 128
#define N_LAYERS 4
#define EPSV 1e-5f
#define NBUCK 1024
#define BSHIFT 7      // 128 nodes per bucket
#define CBLK 4096     // edges per scatter block
#define LSTR 40       // LDS row stride in shorts (80B: 16B-aligned, 2-way-max bank conflicts = free)

using f32x4 = __attribute__((ext_vector_type(4))) float;
using s16x8 = __attribute__((ext_vector_type(8))) short;

__device__ __forceinline__ unsigned short f2bf(float f) {
  union { float f; unsigned u; } c{f};
  unsigned u = c.u;
  return (unsigned short)((u + 0x7fffu + ((u >> 16) & 1u)) >> 16);
}
__device__ __forceinline__ float bf2f(unsigned short s) {
  union { unsigned u; float f; } c{(unsigned)s << 16};
  return c.f;
}

// ---------------- Pass A: dst-bucket AND src-bucket histograms in one pass ----------------
__global__ __launch_bounds__(256) void k_hist2(const int* __restrict__ src, const int* __restrict__ dst,
                                               int* __restrict__ bucket_cnt_d, int* __restrict__ bucket_cnt_s) {
  __shared__ int hd[NBUCK];
  __shared__ int hs[NBUCK];
  for (int i = threadIdx.x; i < NBUCK; i += 256) { hd[i] = 0; hs[i] = 0; }
  __syncthreads();
  int per = (N_EDGES + gridDim.x - 1) / gridDim.x;
  int lo = blockIdx.x * per;
  int hi = lo + per; if (hi > N_EDGES) hi = N_EDGES;
  for (int i = lo + threadIdx.x; i < hi; i += 256) {
    atomicAdd(&hd[dst[i] >> BSHIFT], 1);
    atomicAdd(&hs[src[i] >> BSHIFT], 1);
  }
  __syncthreads();
  for (int i = threadIdx.x; i < NBUCK; i += 256) {
    if (hd[i]) atomicAdd(&bucket_cnt_d[i], hd[i]);
    if (hs[i]) atomicAdd(&bucket_cnt_s[i], hs[i]);
  }
}

// ---------------- Pass B: scan 1024 bucket counts; zero fill ----------------
__global__ __launch_bounds__(256) void k_bscan(const int* __restrict__ cnt, int* __restrict__ base,
                                               int* __restrict__ fill) {
  __shared__ int wsum[4];
  int tid = threadIdx.x;
  int4 v = *(const int4*)(cnt + tid * 4);
  int s4 = v.x + v.y + v.z + v.w;
  int lane = tid & 63, wid = tid >> 6;
  int sc = s4;
#pragma unroll
  for (int off = 1; off < 64; off <<= 1) {
    int u = __shfl_up(sc, off, 64);
    if (lane >= off) sc += u;
  }
  if (lane == 63) wsum[wid] = sc;
  __syncthreads();
  int woff = 0;
#pragma unroll
  for (int w = 0; w < 4; ++w) woff += (w < wid) ? wsum[w] : 0;
  int excl = woff + sc - s4;
  int4 o;
  o.x = excl; o.y = o.x + v.x; o.z = o.y + v.y; o.w = o.z + v.z;
  *(int4*)(base + tid * 4) = o;
  *(int4*)(fill + tid * 4) = make_int4(0, 0, 0, 0);
  if (tid == 255) base[NBUCK] = woff + sc;  // == N_EDGES
}

// ---------------- Pass C: block-local staged scatter of (src,dst) pairs by dst bucket ----------------
__global__ __launch_bounds__(256) void k_scatter2(const int* __restrict__ src, const int* __restrict__ dst,
                                                  const int* __restrict__ bucket_base, int* __restrict__ bucket_fill,
                                                  int2* __restrict__ pairs) {
  __shared__ int hist[NBUCK];
  __shared__ int loff[NBUCK];
  __shared__ int gbase_s[NBUCK];
  __shared__ int lcur[NBUCK];
  __shared__ int wsum[4];
  __shared__ int2 stage[CBLK];                 // 32 KB
  __shared__ unsigned short sbuck[CBLK];       // 8 KB
  int tid = threadIdx.x;
  int e0 = blockIdx.x * CBLK;
  int e1 = e0 + CBLK; if (e1 > N_EDGES) e1 = N_EDGES;
  int n = e1 - e0;
  for (int i = tid; i < NBUCK; i += 256) hist[i] = 0;
  __syncthreads();
  int2 ev[CBLK / 256];
  int nb[CBLK / 256];
#pragma unroll
  for (int j = 0; j < CBLK / 256; ++j) {
    int idx = e0 + j * 256 + tid;
    nb[j] = -1;
    if (idx < e1) {
      ev[j] = make_int2(src[idx], dst[idx]);
      nb[j] = ev[j].y >> BSHIFT;
      atomicAdd(&hist[nb[j]], 1);
    }
  }
  __syncthreads();
  int4 hv = *(const int4*)(hist + tid * 4);
  int s4 = hv.x + hv.y + hv.z + hv.w;
  int lane = tid & 63, wid = tid >> 6;
  int sc = s4;
#pragma unroll
  for (int off = 1; off < 64; off <<= 1) {
    int u = __shfl_up(sc, off, 64);
    if (lane >= off) sc += u;
  }
  if (lane == 63) wsum[wid] = sc;
  __syncthreads();
  int woff = 0;
#pragma unroll
  for (int w = 0; w < 4; ++w) woff += (w < wid) ? wsum[w] : 0;
  int excl = woff + sc - s4;
  loff[tid * 4 + 0] = excl;
  loff[tid * 4 + 1] = excl + hv.x;
  loff[tid * 4 + 2] = excl + hv.x + hv.y;
  loff[tid * 4 + 3] = excl + hv.x + hv.y + hv.z;
  __syncthreads();
  for (int b = tid; b < NBUCK; b += 256) {
    int c = hist[b];
    if (c > 0) gbase_s[b] = bucket_base[b] + atomicAdd(&bucket_fill[b], c);
    lcur[b] = loff[b];
  }
  __syncthreads();
#pragma unroll
  for (int j = 0; j < CBLK / 256; ++j) {
    if (nb[j] >= 0) {
      int p = atomicAdd(&lcur[nb[j]], 1);
      stage[p] = ev[j];
      sbuck[p] = (unsigned short)nb[j];
    }
  }
  __syncthreads();
  for (int s = tid; s < n; s += 256) {
    int b = sbuck[s];
    pairs[gbase_s[b] + (s - loff[b])] = stage[s];
  }
}

// ---------------- Pass C': block-local staged scatter of src values by src bucket ----------------
__global__ __launch_bounds__(256) void k_scatter_src(const int* __restrict__ src,
                                                     const int* __restrict__ base_s, int* __restrict__ fill_s,
                                                     int* __restrict__ svals) {
  __shared__ int hist[NBUCK];
  __shared__ int loff[NBUCK];
  __shared__ int gbase_s[NBUCK];
  __shared__ int lcur[NBUCK];
  __shared__ int wsum[4];
  __shared__ int stage[CBLK];                  // 16 KB
  __shared__ unsigned short sbuck[CBLK];       // 8 KB
  int tid = threadIdx.x;
  int e0 = blockIdx.x * CBLK;
  int e1 = e0 + CBLK; if (e1 > N_EDGES) e1 = N_EDGES;
  int n = e1 - e0;
  for (int i = tid; i < NBUCK; i += 256) hist[i] = 0;
  __syncthreads();
  int ev[CBLK / 256];
  int nb[CBLK / 256];
#pragma unroll
  for (int j = 0; j < CBLK / 256; ++j) {
    int idx = e0 + j * 256 + tid;
    nb[j] = -1;
    if (idx < e1) {
      ev[j] = src[idx];
      nb[j] = ev[j] >> BSHIFT;
      atomicAdd(&hist[nb[j]], 1);
    }
  }
  __syncthreads();
  int4 hv = *(const int4*)(hist + tid * 4);
  int s4 = hv.x + hv.y + hv.z + hv.w;
  int lane = tid & 63, wid = tid >> 6;
  int sc = s4;
#pragma unroll
  for (int off = 1; off < 64; off <<= 1) {
    int u = __shfl_up(sc, off, 64);
    if (lane >= off) sc += u;
  }
  if (lane == 63) wsum[wid] = sc;
  __syncthreads();
  int woff = 0;
#pragma unroll
  for (int w = 0; w < 4; ++w) woff += (w < wid) ? wsum[w] : 0;
  int excl = woff + sc - s4;
  loff[tid * 4 + 0] = excl;
  loff[tid * 4 + 1] = excl + hv.x;
  loff[tid * 4 + 2] = excl + hv.x + hv.y;
  loff[tid * 4 + 3] = excl + hv.x + hv.y + hv.z;
  __syncthreads();
  for (int b = tid; b < NBUCK; b += 256) {
    int c = hist[b];
    if (c > 0) gbase_s[b] = base_s[b] + atomicAdd(&fill_s[b], c);
    lcur[b] = loff[b];
  }
  __syncthreads();
#pragma unroll
  for (int j = 0; j < CBLK / 256; ++j) {
    if (nb[j] >= 0) {
      int p = atomicAdd(&lcur[nb[j]], 1);
      stage[p] = ev[j];
      sbuck[p] = (unsigned short)nb[j];
    }
  }
  __syncthreads();
  for (int s = tid; s < n; s += 256) {
    int b = sbuck[s];
    svals[gbase_s[b] + (s - loff[b])] = stage[s];
  }
}

// ---------------- Pass D': per-src-bucket count -> norm_src (no atomics beyond LDS) ----------------
__global__ __launch_bounds__(256) void k_src_count(const int* __restrict__ svals, const int* __restrict__ base_s,
                                                   float* __restrict__ norm_src) {
  __shared__ int hist[128];
  int bk = blockIdx.x;
  int b0 = base_s[bk], b1 = base_s[bk + 1];
  int tid = threadIdx.x;
  if (tid < 128) hist[tid] = 0;
  __syncthreads();
  for (int i = b0 + tid; i < b1; i += 256) atomicAdd(&hist[svals[i] & 127], 1);
  __syncthreads();
  if (tid < 128) {
    int g = (bk << BSHIFT) + tid;
    if (g < N_NODES) norm_src[g] = hist[tid] > 0 ? rsqrtf((float)hist[tid]) : 0.f;
  }
}

// ---------------- Pass D: per-bucket exact CSR (no global atomics) ----------------
__global__ __launch_bounds__(256) void k_bucket_csr(const int2* __restrict__ pairs, const int* __restrict__ base,
                                                    int* __restrict__ row_ptr, float* __restrict__ norm_dst,
                                                    int* __restrict__ csr_src) {
  __shared__ int hist[128];
  __shared__ int excl[129];
  __shared__ int curs[128];
  int bk = blockIdx.x;
  int b0 = base[bk], b1 = base[bk + 1];
  int tid = threadIdx.x;
  if (tid < 128) hist[tid] = 0;
  __syncthreads();
  for (int i = b0 + tid; i < b1; i += 256) atomicAdd(&hist[pairs[i].y & 127], 1);
  __syncthreads();
  if (tid < 128) {
    int v = hist[tid];
    int lane = tid & 63;
    int sc = v;
#pragma unroll
    for (int off = 1; off < 64; off <<= 1) {
      int u = __shfl_up(sc, off, 64);
      if (lane >= off) sc += u;
    }
    excl[tid] = sc - v;
    if (lane == 63 && tid < 64) excl[128] = sc;
  }
  __syncthreads();
  if (tid >= 64 && tid < 128) excl[tid] += excl[128];
  __syncthreads();
  int gbase = bk << BSHIFT;
  if (tid < 128) {
    int g = gbase + tid;
    if (g < N_NODES) {
      row_ptr[g] = b0 + excl[tid];
      norm_dst[g] = hist[tid] > 0 ? rsqrtf((float)hist[tid]) : 0.f;
    } else if (g == N_NODES) {
      row_ptr[N_NODES] = b0 + excl[tid];
    }
    curs[tid] = excl[tid];
  }
  __syncthreads();
  for (int i = b0 + tid; i < b1; i += 256) {
    int2 p = pairs[i];
    int pos = b0 + atomicAdd(&curs[p.y & 127], 1);
    csr_src[pos] = p.x;
  }
}

// ---------------- embedding lookup: writes x (fp32) + xb (bf16, prescaled by norm_src) ----------------
__global__ __launch_bounds__(256) void k_embed(const int* __restrict__ h, const float* __restrict__ emb,
                                               const float* __restrict__ norm_src,
                                               float* __restrict__ x, unsigned short* __restrict__ xb) {
  int i = blockIdx.x * 256 + threadIdx.x;  // over N*32 float4
  const int total = N_NODES * (HID / 4);
  if (i < total) {
    int r = i >> 5, c = i & 31;
    float4 v = ((const float4*)emb)[h[r] * (HID / 4) + c];
    ((float4*)x)[i] = v;
    float ns = norm_src[r];
    uint2 p;
    p.x = (unsigned)f2bf(v.x * ns) | ((unsigned)f2bf(v.y * ns) << 16);
    p.y = (unsigned)f2bf(v.z * ns) | ((unsigned)f2bf(v.w * ns) << 16);
    *(uint2*)(xb + (size_t)i * 4) = p;
  }
}

// ---------------- W split+transpose: Wt[l][col][k] hi/lo bf16 (GCN layers) ----------------
__global__ __launch_bounds__(128) void k_wsplit(const float* __restrict__ W, unsigned short* __restrict__ Wh,
                                                unsigned short* __restrict__ Wl) {
  int l = blockIdx.x >> 7, k = blockIdx.x & 127;
  int c = threadIdx.x;
  float w = W[(size_t)l * HID * HID + k * HID + c];
  unsigned short h = f2bf(w);
  Wh[(size_t)l * HID * HID + c * HID + k] = h;
  Wl[(size_t)l * HID * HID + c * HID + k] = f2bf(w - bf2f(h));
}

// ---------------- generic W split+transpose for MLP weights: [K][C] -> hi/lo [C][K] ----------------
__global__ __launch_bounds__(256) void k_wsplit_t(const float* __restrict__ Win,
                                                  unsigned short* __restrict__ Wth,
                                                  unsigned short* __restrict__ Wtl, int K, int C) {
  int idx = blockIdx.x * 256 + threadIdx.x;
  if (idx < K * C) {
    int k = idx / C, c = idx - k * C;
    float w = Win[idx];
    unsigned short h = f2bf(w);
    Wth[(size_t)c * K + k] = h;
    Wtl[(size_t)c * K + k] = f2bf(w - bf2f(h));
  }
}

// ---------------- aggregation (prescaled bf16 gather, fp32 accumulate, hi/lo bf16 output) ----------------
__global__ __launch_bounds__(256) void k_agg(const unsigned short* __restrict__ xb, const int* __restrict__ row_ptr,
                                             const int* __restrict__ csr_src, const float* __restrict__ norm_dst,
                                             unsigned short* __restrict__ agg_hi, unsigned short* __restrict__ agg_lo) {
  int node = blockIdx.x * 16 + (threadIdx.x >> 4);
  int l16 = threadIdx.x & 15;
  if (node >= N_NODES) return;
  int s0 = row_ptr[node], s1 = row_ptr[node + 1];
  float acc[8];
#pragma unroll
  for (int j = 0; j < 8; ++j) acc[j] = 0.f;
  int i = s0;
  for (; i + 7 < s1; i += 8) {
    uint4 u[8];
#pragma unroll
    for (int e = 0; e < 8; ++e)
      u[e] = *(const uint4*)(xb + (size_t)csr_src[i + e] * HID + l16 * 8);
#pragma unroll
    for (int e = 0; e < 8; ++e) {
      unsigned uu[4] = {u[e].x, u[e].y, u[e].z, u[e].w};
#pragma unroll
      for (int q = 0; q < 4; ++q) {
        union { unsigned u; float f; } lo{uu[q] << 16}, hi{uu[q] & 0xffff0000u};
        acc[q * 2 + 0] += lo.f;
        acc[q * 2 + 1] += hi.f;
      }
    }
  }
  for (; i + 3 < s1; i += 4) {
    uint4 u[4];
#pragma unroll
    for (int e = 0; e < 4; ++e)
      u[e] = *(const uint4*)(xb + (size_t)csr_src[i + e] * HID + l16 * 8);
#pragma unroll
    for (int e = 0; e < 4; ++e) {
      unsigned uu[4] = {u[e].x, u[e].y, u[e].z, u[e].w};
#pragma unroll
      for (int q = 0; q < 4; ++q) {
        union { unsigned u; float f; } lo{uu[q] << 16}, hi{uu[q] & 0xffff0000u};
        acc[q * 2 + 0] += lo.f;
        acc[q * 2 + 1] += hi.f;
      }
    }
  }
  for (; i < s1; ++i) {
    uint4 u = *(const uint4*)(xb + (size_t)csr_src[i] * HID + l16 * 8);
    unsigned uu[4] = {u.x, u.y, u.z, u.w};
#pragma unroll
    for (int q = 0; q < 4; ++q) {
      union { unsigned u; float f; } lo{uu[q] << 16}, hi{uu[q] & 0xffff0000u};
      acc[q * 2 + 0] += lo.f;
      acc[q * 2 + 1] += hi.f;
    }
  }
  float nd = norm_dst[node];
  unsigned short hh[8], ll[8];
#pragma unroll
  for (int j = 0; j < 8; ++j) {
    float v = acc[j] * nd;
    hh[j] = f2bf(v);
    ll[j] = f2bf(v - bf2f(hh[j]));
  }
  uint4 ho, lo4;
  ho.x = (unsigned)hh[0] | ((unsigned)hh[1] << 16); ho.y = (unsigned)hh[2] | ((unsigned)hh[3] << 16);
  ho.z = (unsigned)hh[4] | ((unsigned)hh[5] << 16); ho.w = (unsigned)hh[6] | ((unsigned)hh[7] << 16);
  lo4.x = (unsigned)ll[0] | ((unsigned)ll[1] << 16); lo4.y = (unsigned)ll[2] | ((unsigned)ll[3] << 16);
  lo4.z = (unsigned)ll[4] | ((unsigned)ll[5] << 16); lo4.w = (unsigned)ll[6] | ((unsigned)ll[7] << 16);
  *(uint4*)(agg_hi + (size_t)node * HID + l16 * 8) = ho;
  *(uint4*)(agg_lo + (size_t)node * HID + l16 * 8) = lo4;
}

// ---------------- MFMA GEMM: Y = A@W + b, bf16x3 (fp32-grade), fused BN stats; Yb output bf16 ----------------
__global__ __launch_bounds__(256, 4) void k_gemm_mfma(const unsigned short* __restrict__ Ah,
                                                      const unsigned short* __restrict__ Al,
                                                      const unsigned short* __restrict__ Bh,
                                                      const unsigned short* __restrict__ Bl,
                                                      const float* __restrict__ bias,
                                                      unsigned short* __restrict__ Y16,
                                                      float* __restrict__ sums, float* __restrict__ sumsq) {
  __shared__ unsigned short sAh[128 * LSTR], sAl[128 * LSTR], sBh[128 * LSTR], sBl[128 * LSTR];  // 40960 B
  const int tid = threadIdx.x;
  const int lane = tid & 63, wid = tid >> 6;
  const int l15 = lane & 15, kg = lane >> 4;
  const int row0 = blockIdx.x * 128;

  f32x4 acc[2][8];
#pragma unroll
  for (int mi = 0; mi < 2; ++mi)
#pragma unroll
    for (int ni = 0; ni < 8; ++ni) acc[mi][ni] = (f32x4){0.f, 0.f, 0.f, 0.f};

  for (int kb = 0; kb < 4; ++kb) {
    const int k0 = kb * 32;
#pragma unroll
    for (int it = 0; it < 2; ++it) {
      int idx = tid * 2 + it;
      int r = idx >> 2, q = idx & 3;
      int gr = row0 + r;
      s16x8 vh = {0, 0, 0, 0, 0, 0, 0, 0}, vl = {0, 0, 0, 0, 0, 0, 0, 0};
      if (gr < N_NODES) {
        vh = *(const s16x8*)(Ah + (size_t)gr * HID + k0 + q * 8);
        vl = *(const s16x8*)(Al + (size_t)gr * HID + k0 + q * 8);
      }
      *(s16x8*)&sAh[r * LSTR + q * 8] = vh;
      *(s16x8*)&sAl[r * LSTR + q * 8] = vl;
      *(s16x8*)&sBh[r * LSTR + q * 8] = *(const s16x8*)(Bh + (size_t)r * HID + k0 + q * 8);
      *(s16x8*)&sBl[r * LSTR + q * 8] = *(const s16x8*)(Bl + (size_t)r * HID + k0 + q * 8);
    }
    __syncthreads();
    s16x8 afh[2], afl[2];
#pragma unroll
    for (int mi = 0; mi < 2; ++mi) {
      int ar = wid * 32 + mi * 16 + l15;
      afh[mi] = *(const s16x8*)&sAh[ar * LSTR + kg * 8];
      afl[mi] = *(const s16x8*)&sAl[ar * LSTR + kg * 8];
    }
#pragma unroll
    for (int ni = 0; ni < 8; ++ni) {
      int bc = ni * 16 + l15;
      s16x8 bh = *(const s16x8*)&sBh[bc * LSTR + kg * 8];
      s16x8 bl = *(const s16x8*)&sBl[bc * LSTR + kg * 8];
#pragma unroll
      for (int mi = 0; mi < 2; ++mi) {
        acc[mi][ni] = __builtin_amdgcn_mfma_f32_16x16x32_bf16(afh[mi], bh, acc[mi][ni], 0, 0, 0);
        acc[mi][ni] = __builtin_amdgcn_mfma_f32_16x16x32_bf16(afh[mi], bl, acc[mi][ni], 0, 0, 0);
        acc[mi][ni] = __builtin_amdgcn_mfma_f32_16x16x32_bf16(afl[mi], bh, acc[mi][ni], 0, 0, 0);
      }
    }
    __syncthreads();
  }

  float bv[8], sp[8], qp[8];
#pragma unroll
  for (int ni = 0; ni < 8; ++ni) {
    bv[ni] = bias[ni * 16 + l15];
    sp[ni] = 0.f; qp[ni] = 0.f;
  }
#pragma unroll
  for (int mi = 0; mi < 2; ++mi) {
    int rbase = row0 + wid * 32 + mi * 16 + kg * 4;
#pragma unroll
    for (int reg = 0; reg < 4; ++reg) {
      int r = rbase + reg;
      if (r < N_NODES) {
        unsigned short* yr = Y16 + (size_t)r * HID;
#pragma unroll
        for (int ni = 0; ni < 8; ++ni) {
          float y = acc[mi][ni][reg] + bv[ni];
          yr[ni * 16 + l15] = f2bf(y);
          sp[ni] += y;
          qp[ni] += y * y;
        }
      }
    }
  }
  __syncthreads();
  float* red_s = (float*)sAh;  // [16][128] = 8KB
  float* red_q = (float*)sBh;
  int slot = wid * 4 + kg;
#pragma unroll
  for (int ni = 0; ni < 8; ++ni) {
    red_s[slot * 128 + ni * 16 + l15] = sp[ni];
    red_q[slot * 128 + ni * 16 + l15] = qp[ni];
  }
  __syncthreads();
  if (tid < 128) {
    float a = 0.f, b2 = 0.f;
#pragma unroll
    for (int s = 0; s < 16; ++s) {
      a += red_s[s * 128 + tid];
      b2 += red_q[s * 128 + tid];
    }
    atomicAdd(&sums[tid], a);
    atomicAdd(&sumsq[tid], b2);
  }
}

// ---------------- BN finalize ----------------
__global__ __launch_bounds__(128) void k_bn_final(const float* __restrict__ sums, const float* __restrict__ sumsq,
                                                  const float* __restrict__ gamma, const float* __restrict__ beta,
                                                  float* __restrict__ scale, float* __restrict__ shift) {
  int d = threadIdx.x;
  float mu = sums[d] / (float)N_NODES;
  float var = sumsq[d] / (float)N_NODES - mu * mu;
  float sc = gamma[d] * rsqrtf(var + EPSV);
  scale[d] = sc;
  shift[d] = beta[d] - mu * sc;
}

// ---------------- BN apply + relu + residual; Yb bf16 in; writes x (fp32) + xb (bf16, prescaled) ----------------
__global__ __launch_bounds__(256) void k_bn_apply(const unsigned short* __restrict__ Y16,
                                                  const float* __restrict__ scale,
                                                  const float* __restrict__ shift, const float* __restrict__ norm_src,
                                                  float* __restrict__ x, unsigned short* __restrict__ xb) {
  int i = blockIdx.x * 256 + threadIdx.x;  // over N*16 chunks of 8 cols
  const int total = N_NODES * (HID / 8);
  if (i >= total) return;
  int c8 = i & 15, r = i >> 4;
  uint4 yu = *(const uint4*)(Y16 + (size_t)r * HID + c8 * 8);
  unsigned yw[4] = {yu.x, yu.y, yu.z, yu.w};
  float y[8];
#pragma unroll
  for (int q = 0; q < 4; ++q) {
    union { unsigned u; float f; } lo{yw[q] << 16}, hi{yw[q] & 0xffff0000u};
    y[q * 2 + 0] = lo.f;
    y[q * 2 + 1] = hi.f;
  }
  float4 sc0 = *(const float4*)(scale + c8 * 8);
  float4 sc1 = *(const float4*)(scale + c8 * 8 + 4);
  float4 sh0 = *(const float4*)(shift + c8 * 8);
  float4 sh1 = *(const float4*)(shift + c8 * 8 + 4);
  float scv[8] = {sc0.x, sc0.y, sc0.z, sc0.w, sc1.x, sc1.y, sc1.z, sc1.w};
  float shv[8] = {sh0.x, sh0.y, sh0.z, sh0.w, sh1.x, sh1.y, sh1.z, sh1.w};
  float* xr = x + (size_t)r * HID + c8 * 8;
  float4 x0 = *(const float4*)xr;
  float4 x1 = *(const float4*)(xr + 4);
  float xv[8] = {x0.x, x0.y, x0.z, x0.w, x1.x, x1.y, x1.z, x1.w};
  float o[8];
#pragma unroll
  for (int q = 0; q < 8; ++q) o[q] = fmaxf(y[q] * scv[q] + shv[q], 0.f) + xv[q];
  *(float4*)xr = make_float4(o[0], o[1], o[2], o[3]);
  *(float4*)(xr + 4) = make_float4(o[4], o[5], o[6], o[7]);
  float ns = norm_src[r];
  uint4 p;
  p.x = (unsigned)f2bf(o[0] * ns) | ((unsigned)f2bf(o[1] * ns) << 16);
  p.y = (unsigned)f2bf(o[2] * ns) | ((unsigned)f2bf(o[3] * ns) << 16);
  p.z = (unsigned)f2bf(o[4] * ns) | ((unsigned)f2bf(o[5] * ns) << 16);
  p.w = (unsigned)f2bf(o[6] * ns) | ((unsigned)f2bf(o[7] * ns) << 16);
  *(uint4*)(xb + (size_t)r * HID + c8 * 8) = p;
}

// ---------------- MFMA readout: BN(l=3) + residual -> 128->64->32->6 (Yb bf16 in) ----------------
__global__ __launch_bounds__(256, 4) void k_readout(const unsigned short* __restrict__ Y16,
                                                    const float* __restrict__ Xres,
                                                    const float* __restrict__ scale, const float* __restrict__ shift,
                                                    const unsigned short* __restrict__ B1h, const unsigned short* __restrict__ B1l,
                                                    const float* __restrict__ b1,
                                                    const unsigned short* __restrict__ B2h, const unsigned short* __restrict__ B2l,
                                                    const float* __restrict__ b2,
                                                    const float* __restrict__ W3, const float* __restrict__ b3,
                                                    float* __restrict__ out) {
  __shared__ unsigned short sAh[128 * 72], sAl[128 * 72];  // 36864 B
  __shared__ float scs[128], shs[128];
  __shared__ float Ws3s[192];
  const int tid = threadIdx.x;
  const int lane = tid & 63, wid = tid >> 6;
  const int l15 = lane & 15, kg = lane >> 4;
  const int row0 = blockIdx.x * 128;
  if (tid < 128) { scs[tid] = scale[tid]; shs[tid] = shift[tid]; }
  if (tid < 192) Ws3s[tid] = W3[tid];
  __syncthreads();

  f32x4 acc1[2][4];
#pragma unroll
  for (int mi = 0; mi < 2; ++mi)
#pragma unroll
    for (int ni = 0; ni < 4; ++ni) acc1[mi][ni] = (f32x4){0.f, 0.f, 0.f, 0.f};

  // ---- layer 1: two K-slabs of 64 ----
  for (int slab = 0; slab < 2; ++slab) {
    const int c0 = slab * 64;
#pragma unroll
    for (int it = 0; it < 4; ++it) {
      int idx = tid + it * 256;        // 0..1023
      int r = idx >> 3, q = idx & 7;   // row, 8-col chunk
      int gr = row0 + r;
      float v[8];
      if (gr < N_NODES) {
        uint4 yu = *(const uint4*)(Y16 + (size_t)gr * HID + c0 + q * 8);
        unsigned yw[4] = {yu.x, yu.y, yu.z, yu.w};
        const float* xp = Xres + (size_t)gr * HID + c0 + q * 8;
        float4 x0 = *(const float4*)xp, x1 = *(const float4*)(xp + 4);
        float xvv[8] = {x0.x, x0.y, x0.z, x0.w, x1.x, x1.y, x1.z, x1.w};
        const float* scp = &scs[c0 + q * 8];
        const float* shp = &shs[c0 + q * 8];
#pragma unroll
        for (int qq = 0; qq < 4; ++qq) {
          union { unsigned u; float f; } lo{yw[qq] << 16}, hi{yw[qq] & 0xffff0000u};
          v[qq * 2 + 0] = fmaxf(lo.f * scp[qq * 2 + 0] + shp[qq * 2 + 0], 0.f) + xvv[qq * 2 + 0];
          v[qq * 2 + 1] = fmaxf(hi.f * scp[qq * 2 + 1] + shp[qq * 2 + 1], 0.f) + xvv[qq * 2 + 1];
        }
      } else {
#pragma unroll
        for (int j = 0; j < 8; ++j) v[j] = 0.f;
      }
      short hh[8], ll[8];
#pragma unroll
      for (int j = 0; j < 8; ++j) {
        unsigned short hb = f2bf(v[j]);
        hh[j] = (short)hb;
        ll[j] = (short)f2bf(v[j] - bf2f(hb));
      }
      *(s16x8*)&sAh[r * 72 + q * 8] = (s16x8){hh[0], hh[1], hh[2], hh[3], hh[4], hh[5], hh[6], hh[7]};
      *(s16x8*)&sAl[r * 72 + q * 8] = (s16x8){ll[0], ll[1], ll[2], ll[3], ll[4], ll[5], ll[6], ll[7]};
    }
    __syncthreads();
#pragma unroll
    for (int kb = 0; kb < 2; ++kb) {
      s16x8 afh[2], afl[2];
#pragma unroll
      for (int mi = 0; mi < 2; ++mi) {
        int ar = wid * 32 + mi * 16 + l15;
        afh[mi] = *(const s16x8*)&sAh[ar * 72 + kb * 32 + kg * 8];
        afl[mi] = *(const s16x8*)&sAl[ar * 72 + kb * 32 + kg * 8];
      }
#pragma unroll
      for (int ni = 0; ni < 4; ++ni) {
        int bc = ni * 16 + l15;
        s16x8 bh = *(const s16x8*)(B1h + (size_t)bc * 128 + c0 + kb * 32 + kg * 8);
        s16x8 bl = *(const s16x8*)(B1l + (size_t)bc * 128 + c0 + kb * 32 + kg * 8);
#pragma unroll
        for (int mi = 0; mi < 2; ++mi) {
          acc1[mi][ni] = __builtin_amdgcn_mfma_f32_16x16x32_bf16(afh[mi], bh, acc1[mi][ni], 0, 0, 0);
          acc1[mi][ni] = __builtin_amdgcn_mfma_f32_16x16x32_bf16(afh[mi], bl, acc1[mi][ni], 0, 0, 0);
          acc1[mi][ni] = __builtin_amdgcn_mfma_f32_16x16x32_bf16(afl[mi], bh, acc1[mi][ni], 0, 0, 0);
        }
      }
    }
    __syncthreads();
  }

  // ---- h1 = relu(acc1 + b1) -> LDS hi/lo ----
  float bv1[4];
#pragma unroll
  for (int ni = 0; ni < 4; ++ni) bv1[ni] = b1[ni * 16 + l15];
#pragma unroll
  for (int mi = 0; mi < 2; ++mi)
#pragma unroll
    for (int ni = 0; ni < 4; ++ni)
#pragma unroll
      for (int reg = 0; reg < 4; ++reg) {
        int rr = wid * 32 + mi * 16 + kg * 4 + reg;
        float v = fmaxf(acc1[mi][ni][reg] + bv1[ni], 0.f);
        unsigned short hb = f2bf(v);
        sAh[rr * 72 + ni * 16 + l15] = hb;
        sAl[rr * 72 + ni * 16 + l15] = f2bf(v - bf2f(hb));
      }
  __syncthreads();

  // ---- layer 2 via MFMA, K=64 ----
  f32x4 acc2[2][2];
#pragma unroll
  for (int mi = 0; mi < 2; ++mi)
#pragma unroll
    for (int ni = 0; ni < 2; ++ni) acc2[mi][ni] = (f32x4){0.f, 0.f, 0.f, 0.f};
#pragma unroll
  for (int kb = 0; kb < 2; ++kb) {
    s16x8 afh[2], afl[2];
#pragma unroll
    for (int mi = 0; mi < 2; ++mi) {
      int ar = wid * 32 + mi * 16 + l15;
      afh[mi] = *(const s16x8*)&sAh[ar * 72 + kb * 32 + kg * 8];
      afl[mi] = *(const s16x8*)&sAl[ar * 72 + kb * 32 + kg * 8];
    }
#pragma unroll
    for (int ni = 0; ni < 2; ++ni) {
      int bc = ni * 16 + l15;
      s16x8 bh = *(const s16x8*)(B2h + (size_t)bc * 64 + kb * 32 + kg * 8);
      s16x8 bl = *(const s16x8*)(B2l + (size_t)bc * 64 + kb * 32 + kg * 8);
#pragma unroll
      for (int mi = 0; mi < 2; ++mi) {
        acc2[mi][ni] = __builtin_amdgcn_mfma_f32_16x16x32_bf16(afh[mi], bh, acc2[mi][ni], 0, 0, 0);
        acc2[mi][ni] = __builtin_amdgcn_mfma_f32_16x16x32_bf16(afh[mi], bl, acc2[mi][ni], 0, 0, 0);
        acc2[mi][ni] = __builtin_amdgcn_mfma_f32_16x16x32_bf16(afl[mi], bh, acc2[mi][ni], 0, 0, 0);
      }
    }
  }
  __syncthreads();

  // ---- h2 = relu(acc2 + b2) -> LDS fp32 [128][36] ----
  float* h2s = (float*)sAh;
  float bv2[2];
#pragma unroll
  for (int ni = 0; ni < 2; ++ni) bv2[ni] = b2[ni * 16 + l15];
#pragma unroll
  for (int mi = 0; mi < 2; ++mi)
#pragma unroll
    for (int ni = 0; ni < 2; ++ni)
#pragma unroll
      for (int reg = 0; reg < 4; ++reg) {
        int rr = wid * 32 + mi * 16 + kg * 4 + reg;
        h2s[rr * 36 + ni * 16 + l15] = fmaxf(acc2[mi][ni][reg] + bv2[ni], 0.f);
      }
  __syncthreads();

  // ---- layer 3: per-thread ----
  if (tid < 128) {
    int gr = row0 + tid;
    if (gr < N_NODES) {
      float h2r[32];
#pragma unroll
      for (int q = 0; q < 8; ++q) {
        float4 t = *(const float4*)&h2s[tid * 36 + q * 4];
        h2r[q * 4 + 0] = t.x; h2r[q * 4 + 1] = t.y; h2r[q * 4 + 2] = t.z; h2r[q * 4 + 3] = t.w;
      }
      float p[6];
#pragma unroll
      for (int o = 0; o < 6; ++o) p[o] = b3[o];
#pragma unroll
      for (int k = 0; k < 32; ++k)
#pragma unroll
        for (int o = 0; o < 6; ++o) p[o] += h2r[k] * Ws3s[k * 6 + o];
      float* orow = out + (size_t)gr * 6;
#pragma unroll
      for (int o = 0; o < 6; ++o) orow[o] = p[o];
    }
  }
}

extern "C" void kernel_launch(void* const* d_in, const int* in_sizes, int n_in,
                              void* d_out, int out_size, void* d_ws, size_t ws_size,
                              hipStream_t stream) {
  const int* h = (const int*)d_in[0];
  const int* src = (const int*)d_in[1];
  const int* dst = (const int*)d_in[2];
  const float* emb = (const float*)d_in[3];
  const float* W = (const float*)d_in[4];
  const float* b = (const float*)d_in[5];
  const float* gamma = (const float*)d_in[6];
  const float* beta = (const float*)d_in[7];
  const float* W1 = (const float*)d_in[8];
  const float* b1 = (const float*)d_in[9];
  const float* W2 = (const float*)d_in[10];
  const float* b2 = (const float*)d_in[11];
  const float* W3 = (const float*)d_in[12];
  const float* b3 = (const float*)d_in[13];
  float* out = (float*)d_out;

  char* ws = (char*)d_ws;
  size_t off = 0;
  auto alloc = [&](size_t bytes) -> void* {
    void* p = ws + off;
    off += (bytes + 255) & ~(size_t)255;
    return p;
  };
  float* norm_src = (float*)alloc(N_NODES * 4);
  float* norm_dst = (float*)alloc(N_NODES * 4);
  int* row_ptr = (int*)alloc((N_NODES + 1) * 4);
  int* csr_src = (int*)alloc((size_t)N_EDGES * 4);
  int* bucket_cnt_d = (int*)alloc(NBUCK * 4);
  int* bucket_base_d = (int*)alloc((NBUCK + 1) * 4);
  int* bucket_fill_d = (int*)alloc(NBUCK * 4);
  int* bucket_cnt_s = (int*)alloc(NBUCK * 4);
  int* bucket_base_s = (int*)alloc((NBUCK + 1) * 4);
  int* bucket_fill_s = (int*)alloc(NBUCK * 4);
  float* x = (float*)alloc((size_t)N_NODES * HID * 4);
  unsigned short* xb = (unsigned short*)alloc((size_t)N_NODES * HID * 2);
  unsigned short* agg_hi = (unsigned short*)alloc((size_t)N_NODES * HID * 2);
  unsigned short* agg_lo = (unsigned short*)alloc((size_t)N_NODES * HID * 2);
  unsigned short* Yb16 = (unsigned short*)alloc((size_t)N_NODES * HID * 2);
  unsigned short* Wh = (unsigned short*)alloc((size_t)N_LAYERS * HID * HID * 2);
  unsigned short* Wl = (unsigned short*)alloc((size_t)N_LAYERS * HID * HID * 2);
  unsigned short* B1h = (unsigned short*)alloc(64 * 128 * 2);
  unsigned short* B1l = (unsigned short*)alloc(64 * 128 * 2);
  unsigned short* B2h = (unsigned short*)alloc(32 * 64 * 2);
  unsigned short* B2l = (unsigned short*)alloc(32 * 64 * 2);
  float* sums = (float*)alloc(512);
  float* sumsq = (float*)alloc(512);
  float* scale = (float*)alloc(512);
  float* shift = (float*)alloc(512);
  int2* pairs = (int2*)alloc((size_t)N_EDGES * 8);  // 12.8MB
  int* svals = (int*)alloc((size_t)N_EDGES * 4);    // 6.4MB

  hipMemsetAsync(bucket_cnt_d, 0, NBUCK * 4, stream);
  hipMemsetAsync(bucket_cnt_s, 0, NBUCK * 4, stream);
  k_hist2<<<1024, 256, 0, stream>>>(src, dst, bucket_cnt_d, bucket_cnt_s);
  k_bscan<<<1, 256, 0, stream>>>(bucket_cnt_d, bucket_base_d, bucket_fill_d);
  k_bscan<<<1, 256, 0, stream>>>(bucket_cnt_s, bucket_base_s, bucket_fill_s);
  k_scatter2<<<(N_EDGES + CBLK - 1) / CBLK, 256, 0, stream>>>(src, dst, bucket_base_d, bucket_fill_d, pairs);
  k_scatter_src<<<(N_EDGES + CBLK - 1) / CBLK, 256, 0, stream>>>(src, bucket_base_s, bucket_fill_s, svals);
  k_bucket_csr<<<NBUCK, 256, 0, stream>>>(pairs, bucket_base_d, row_ptr, norm_dst, csr_src);
  k_src_count<<<NBUCK, 256, 0, stream>>>(svals, bucket_base_s, norm_src);
  k_embed<<<(N_NODES * (HID / 4) + 255) / 256, 256, 0, stream>>>(h, emb, norm_src, x, xb);
  k_wsplit<<<N_LAYERS * 128, 128, 0, stream>>>(W, Wh, Wl);
  k_wsplit_t<<<(128 * 64 + 255) / 256, 256, 0, stream>>>(W1, B1h, B1l, 128, 64);
  k_wsplit_t<<<(64 * 32 + 255) / 256, 256, 0, stream>>>(W2, B2h, B2l, 64, 32);

  for (int l = 0; l < N_LAYERS; ++l) {
    k_agg<<<(N_NODES + 15) / 16, 256, 0, stream>>>(xb, row_ptr, csr_src, norm_dst, agg_hi, agg_lo);
    hipMemsetAsync(sums, 0, 1024, stream);  // sums+sumsq contiguous
    k_gemm_mfma<<<(N_NODES + 127) / 128, 256, 0, stream>>>(agg_hi, agg_lo,
                                                           Wh + (size_t)l * HID * HID, Wl + (size_t)l * HID * HID,
                                                           b + l * HID, Yb16, sums, sumsq);
    k_bn_final<<<1, 128, 0, stream>>>(sums, sumsq, gamma + l * HID, beta + l * HID, scale, shift);
    if (l < N_LAYERS - 1) {
      k_bn_apply<<<(N_NODES * (HID / 8) + 255) / 256, 256, 0, stream>>>(Yb16, scale, shift, norm_src, x, xb);
    }
  }
  k_readout<<<(N_NODES + 127) / 128, 256, 0, stream>>>(Yb16, x, scale, shift,
                                                       B1h, B1l, b1, B2h, B2l, b2, W3, b3, out);
}

// Round 17
// 616.855 us; speedup vs baseline: 1.1006x; 1.0491x over previous
//
#include <hip/hip_runtime.h>

#define N_NODES 100000
#define N_EDGES 1600000
#define HID 128
#define N_LAYERS 4
#define EPSV 1e-5f
#define NBUCK 1024
#define BSHIFT 7      // 128 nodes per bucket
#define CBLK 4096     // edges per scatter block
#define VOCAB 7
#define LSTR 40       // LDS row stride in shorts (80B: 16B-aligned, 2-way-max bank conflicts = free)

using f32x4 = __attribute__((ext_vector_type(4))) float;
using s16x8 = __attribute__((ext_vector_type(8))) short;

__device__ __forceinline__ unsigned short f2bf(float f) {
  union { float f; unsigned u; } c{f};
  unsigned u = c.u;
  return (unsigned short)((u + 0x7fffu + ((u >> 16) & 1u)) >> 16);
}
__device__ __forceinline__ float bf2f(unsigned short s) {
  union { unsigned u; float f; } c{(unsigned)s << 16};
  return c.f;
}

// ---------------- Pass A: dst-bucket AND src-bucket histograms in one pass ----------------
__global__ __launch_bounds__(256) void k_hist2(const int* __restrict__ src, const int* __restrict__ dst,
                                               int* __restrict__ bucket_cnt_d, int* __restrict__ bucket_cnt_s) {
  __shared__ int hd[NBUCK];
  __shared__ int hs[NBUCK];
  for (int i = threadIdx.x; i < NBUCK; i += 256) { hd[i] = 0; hs[i] = 0; }
  __syncthreads();
  int per = (N_EDGES + gridDim.x - 1) / gridDim.x;
  int lo = blockIdx.x * per;
  int hi = lo + per; if (hi > N_EDGES) hi = N_EDGES;
  for (int i = lo + threadIdx.x; i < hi; i += 256) {
    atomicAdd(&hd[dst[i] >> BSHIFT], 1);
    atomicAdd(&hs[src[i] >> BSHIFT], 1);
  }
  __syncthreads();
  for (int i = threadIdx.x; i < NBUCK; i += 256) {
    if (hd[i]) atomicAdd(&bucket_cnt_d[i], hd[i]);
    if (hs[i]) atomicAdd(&bucket_cnt_s[i], hs[i]);
  }
}

// ---------------- Pass B: scan 1024 bucket counts; zero fill ----------------
__global__ __launch_bounds__(256) void k_bscan(const int* __restrict__ cnt, int* __restrict__ base,
                                               int* __restrict__ fill) {
  __shared__ int wsum[4];
  int tid = threadIdx.x;
  int4 v = *(const int4*)(cnt + tid * 4);
  int s4 = v.x + v.y + v.z + v.w;
  int lane = tid & 63, wid = tid >> 6;
  int sc = s4;
#pragma unroll
  for (int off = 1; off < 64; off <<= 1) {
    int u = __shfl_up(sc, off, 64);
    if (lane >= off) sc += u;
  }
  if (lane == 63) wsum[wid] = sc;
  __syncthreads();
  int woff = 0;
#pragma unroll
  for (int w = 0; w < 4; ++w) woff += (w < wid) ? wsum[w] : 0;
  int excl = woff + sc - s4;
  int4 o;
  o.x = excl; o.y = o.x + v.x; o.z = o.y + v.y; o.w = o.z + v.z;
  *(int4*)(base + tid * 4) = o;
  *(int4*)(fill + tid * 4) = make_int4(0, 0, 0, 0);
  if (tid == 255) base[NBUCK] = woff + sc;  // == N_EDGES
}

// ---------------- Pass C: block-local staged scatter of (src,dst) pairs by dst bucket ----------------
__global__ __launch_bounds__(256) void k_scatter2(const int* __restrict__ src, const int* __restrict__ dst,
                                                  const int* __restrict__ bucket_base, int* __restrict__ bucket_fill,
                                                  int2* __restrict__ pairs) {
  __shared__ int hist[NBUCK];
  __shared__ int loff[NBUCK];
  __shared__ int gbase_s[NBUCK];
  __shared__ int lcur[NBUCK];
  __shared__ int wsum[4];
  __shared__ int2 stage[CBLK];                 // 32 KB
  __shared__ unsigned short sbuck[CBLK];       // 8 KB
  int tid = threadIdx.x;
  int e0 = blockIdx.x * CBLK;
  int e1 = e0 + CBLK; if (e1 > N_EDGES) e1 = N_EDGES;
  int n = e1 - e0;
  for (int i = tid; i < NBUCK; i += 256) hist[i] = 0;
  __syncthreads();
  int2 ev[CBLK / 256];
  int nb[CBLK / 256];
#pragma unroll
  for (int j = 0; j < CBLK / 256; ++j) {
    int idx = e0 + j * 256 + tid;
    nb[j] = -1;
    if (idx < e1) {
      ev[j] = make_int2(src[idx], dst[idx]);
      nb[j] = ev[j].y >> BSHIFT;
      atomicAdd(&hist[nb[j]], 1);
    }
  }
  __syncthreads();
  int4 hv = *(const int4*)(hist + tid * 4);
  int s4 = hv.x + hv.y + hv.z + hv.w;
  int lane = tid & 63, wid = tid >> 6;
  int sc = s4;
#pragma unroll
  for (int off = 1; off < 64; off <<= 1) {
    int u = __shfl_up(sc, off, 64);
    if (lane >= off) sc += u;
  }
  if (lane == 63) wsum[wid] = sc;
  __syncthreads();
  int woff = 0;
#pragma unroll
  for (int w = 0; w < 4; ++w) woff += (w < wid) ? wsum[w] : 0;
  int excl = woff + sc - s4;
  loff[tid * 4 + 0] = excl;
  loff[tid * 4 + 1] = excl + hv.x;
  loff[tid * 4 + 2] = excl + hv.x + hv.y;
  loff[tid * 4 + 3] = excl + hv.x + hv.y + hv.z;
  __syncthreads();
  for (int b = tid; b < NBUCK; b += 256) {
    int c = hist[b];
    if (c > 0) gbase_s[b] = bucket_base[b] + atomicAdd(&bucket_fill[b], c);
    lcur[b] = loff[b];
  }
  __syncthreads();
#pragma unroll
  for (int j = 0; j < CBLK / 256; ++j) {
    if (nb[j] >= 0) {
      int p = atomicAdd(&lcur[nb[j]], 1);
      stage[p] = ev[j];
      sbuck[p] = (unsigned short)nb[j];
    }
  }
  __syncthreads();
  for (int s = tid; s < n; s += 256) {
    int b = sbuck[s];
    pairs[gbase_s[b] + (s - loff[b])] = stage[s];
  }
}

// ---------------- Pass C': block-local staged scatter of src values by src bucket ----------------
__global__ __launch_bounds__(256) void k_scatter_src(const int* __restrict__ src,
                                                     const int* __restrict__ base_s, int* __restrict__ fill_s,
                                                     int* __restrict__ svals) {
  __shared__ int hist[NBUCK];
  __shared__ int loff[NBUCK];
  __shared__ int gbase_s[NBUCK];
  __shared__ int lcur[NBUCK];
  __shared__ int wsum[4];
  __shared__ int stage[CBLK];                  // 16 KB
  __shared__ unsigned short sbuck[CBLK];       // 8 KB
  int tid = threadIdx.x;
  int e0 = blockIdx.x * CBLK;
  int e1 = e0 + CBLK; if (e1 > N_EDGES) e1 = N_EDGES;
  int n = e1 - e0;
  for (int i = tid; i < NBUCK; i += 256) hist[i] = 0;
  __syncthreads();
  int ev[CBLK / 256];
  int nb[CBLK / 256];
#pragma unroll
  for (int j = 0; j < CBLK / 256; ++j) {
    int idx = e0 + j * 256 + tid;
    nb[j] = -1;
    if (idx < e1) {
      ev[j] = src[idx];
      nb[j] = ev[j] >> BSHIFT;
      atomicAdd(&hist[nb[j]], 1);
    }
  }
  __syncthreads();
  int4 hv = *(const int4*)(hist + tid * 4);
  int s4 = hv.x + hv.y + hv.z + hv.w;
  int lane = tid & 63, wid = tid >> 6;
  int sc = s4;
#pragma unroll
  for (int off = 1; off < 64; off <<= 1) {
    int u = __shfl_up(sc, off, 64);
    if (lane >= off) sc += u;
  }
  if (lane == 63) wsum[wid] = sc;
  __syncthreads();
  int woff = 0;
#pragma unroll
  for (int w = 0; w < 4; ++w) woff += (w < wid) ? wsum[w] : 0;
  int excl = woff + sc - s4;
  loff[tid * 4 + 0] = excl;
  loff[tid * 4 + 1] = excl + hv.x;
  loff[tid * 4 + 2] = excl + hv.x + hv.y;
  loff[tid * 4 + 3] = excl + hv.x + hv.y + hv.z;
  __syncthreads();
  for (int b = tid; b < NBUCK; b += 256) {
    int c = hist[b];
    if (c > 0) gbase_s[b] = base_s[b] + atomicAdd(&fill_s[b], c);
    lcur[b] = loff[b];
  }
  __syncthreads();
#pragma unroll
  for (int j = 0; j < CBLK / 256; ++j) {
    if (nb[j] >= 0) {
      int p = atomicAdd(&lcur[nb[j]], 1);
      stage[p] = ev[j];
      sbuck[p] = (unsigned short)nb[j];
    }
  }
  __syncthreads();
  for (int s = tid; s < n; s += 256) {
    int b = sbuck[s];
    svals[gbase_s[b] + (s - loff[b])] = stage[s];
  }
}

// ---------------- Pass D': per-src-bucket count -> norm_src ----------------
__global__ __launch_bounds__(256) void k_src_count(const int* __restrict__ svals, const int* __restrict__ base_s,
                                                   float* __restrict__ norm_src) {
  __shared__ int hist[128];
  int bk = blockIdx.x;
  int b0 = base_s[bk], b1 = base_s[bk + 1];
  int tid = threadIdx.x;
  if (tid < 128) hist[tid] = 0;
  __syncthreads();
  for (int i = b0 + tid; i < b1; i += 256) atomicAdd(&hist[svals[i] & 127], 1);
  __syncthreads();
  if (tid < 128) {
    int g = (bk << BSHIFT) + tid;
    if (g < N_NODES) norm_src[g] = hist[tid] > 0 ? rsqrtf((float)hist[tid]) : 0.f;
  }
}

// ---------------- Pass D: per-bucket exact CSR (no global atomics) ----------------
__global__ __launch_bounds__(256) void k_bucket_csr(const int2* __restrict__ pairs, const int* __restrict__ base,
                                                    int* __restrict__ row_ptr, float* __restrict__ norm_dst,
                                                    int* __restrict__ csr_src) {
  __shared__ int hist[128];
  __shared__ int excl[129];
  __shared__ int curs[128];
  int bk = blockIdx.x;
  int b0 = base[bk], b1 = base[bk + 1];
  int tid = threadIdx.x;
  if (tid < 128) hist[tid] = 0;
  __syncthreads();
  for (int i = b0 + tid; i < b1; i += 256) atomicAdd(&hist[pairs[i].y & 127], 1);
  __syncthreads();
  if (tid < 128) {
    int v = hist[tid];
    int lane = tid & 63;
    int sc = v;
#pragma unroll
    for (int off = 1; off < 64; off <<= 1) {
      int u = __shfl_up(sc, off, 64);
      if (lane >= off) sc += u;
    }
    excl[tid] = sc - v;
    if (lane == 63 && tid < 64) excl[128] = sc;
  }
  __syncthreads();
  if (tid >= 64 && tid < 128) excl[tid] += excl[128];
  __syncthreads();
  int gbase = bk << BSHIFT;
  if (tid < 128) {
    int g = gbase + tid;
    if (g < N_NODES) {
      row_ptr[g] = b0 + excl[tid];
      norm_dst[g] = hist[tid] > 0 ? rsqrtf((float)hist[tid]) : 0.f;
    } else if (g == N_NODES) {
      row_ptr[N_NODES] = b0 + excl[tid];
    }
    curs[tid] = excl[tid];
  }
  __syncthreads();
  for (int i = b0 + tid; i < b1; i += 256) {
    int2 p = pairs[i];
    int pos = b0 + atomicAdd(&curs[p.y & 127], 1);
    csr_src[pos] = p.x;
  }
}

// ---------------- embedding lookup: writes x (fp32 residual only) ----------------
__global__ __launch_bounds__(256) void k_embed(const int* __restrict__ h, const float* __restrict__ emb,
                                               float* __restrict__ x) {
  int i = blockIdx.x * 256 + threadIdx.x;  // over N*32 float4
  const int total = N_NODES * (HID / 4);
  if (i < total) {
    int r = i >> 5, c = i & 31;
    ((float4*)x)[i] = ((const float4*)emb)[h[r] * (HID / 4) + c];
  }
}

// ---------------- layer-1 aggregation via class weights (VOCAB=7 trick) ----------------
// agg1[n] = norm_dst[n] * sum_v cw[v] * emb[v], cw[v] = sum of norm_src over neighbors with h==v.
// 4 lanes/node; 8B gathered per edge (h[s], norm_src[s]) instead of 256B.
__global__ __launch_bounds__(256) void k_agg1(const int* __restrict__ row_ptr, const int* __restrict__ csr_src,
                                              const int* __restrict__ h, const float* __restrict__ norm_src,
                                              const float* __restrict__ norm_dst, const float* __restrict__ emb,
                                              unsigned short* __restrict__ agg_hi, unsigned short* __restrict__ agg_lo) {
  __shared__ float embs[VOCAB * HID];  // 3.5 KB
  int tid = threadIdx.x;
  for (int i = tid; i < VOCAB * HID; i += 256) embs[i] = emb[i];
  __syncthreads();
  int node = blockIdx.x * 64 + (tid >> 2);
  int l4 = tid & 3;
  if (node >= N_NODES) return;
  int s0 = row_ptr[node], s1 = row_ptr[node + 1];
  float cw[VOCAB];
#pragma unroll
  for (int v = 0; v < VOCAB; ++v) cw[v] = 0.f;
  for (int i = s0 + l4; i < s1; i += 4) {
    int s = csr_src[i];
    int v = h[s];
    float ns = norm_src[s];
#pragma unroll
    for (int vv = 0; vv < VOCAB; ++vv) cw[vv] += (v == vv) ? ns : 0.f;
  }
  // reduce across the 4-lane group
#pragma unroll
  for (int v = 0; v < VOCAB; ++v) {
    cw[v] += __shfl_xor(cw[v], 1, 64);
    cw[v] += __shfl_xor(cw[v], 2, 64);
  }
  float nd = norm_dst[node];
  // each lane computes cols l4*32 .. +31
  unsigned short* oh = agg_hi + (size_t)node * HID + l4 * 32;
  unsigned short* ol = agg_lo + (size_t)node * HID + l4 * 32;
#pragma unroll
  for (int q = 0; q < 4; ++q) {  // 8 cols per chunk
    unsigned short hh[8], ll[8];
#pragma unroll
    for (int c = 0; c < 8; ++c) {
      int col = l4 * 32 + q * 8 + c;
      float s = 0.f;
#pragma unroll
      for (int v = 0; v < VOCAB; ++v) s += cw[v] * embs[v * HID + col];
      float val = s * nd;
      hh[c] = f2bf(val);
      ll[c] = f2bf(val - bf2f(hh[c]));
    }
    uint4 ho, lo4;
    ho.x = (unsigned)hh[0] | ((unsigned)hh[1] << 16); ho.y = (unsigned)hh[2] | ((unsigned)hh[3] << 16);
    ho.z = (unsigned)hh[4] | ((unsigned)hh[5] << 16); ho.w = (unsigned)hh[6] | ((unsigned)hh[7] << 16);
    lo4.x = (unsigned)ll[0] | ((unsigned)ll[1] << 16); lo4.y = (unsigned)ll[2] | ((unsigned)ll[3] << 16);
    lo4.z = (unsigned)ll[4] | ((unsigned)ll[5] << 16); lo4.w = (unsigned)ll[6] | ((unsigned)ll[7] << 16);
    *(uint4*)(oh + q * 8) = ho;
    *(uint4*)(ol + q * 8) = lo4;
  }
}

// ---------------- W split+transpose: Wt[l][col][k] hi/lo bf16 (GCN layers) ----------------
__global__ __launch_bounds__(128) void k_wsplit(const float* __restrict__ W, unsigned short* __restrict__ Wh,
                                                unsigned short* __restrict__ Wl) {
  int l = blockIdx.x >> 7, k = blockIdx.x & 127;
  int c = threadIdx.x;
  float w = W[(size_t)l * HID * HID + k * HID + c];
  unsigned short h = f2bf(w);
  Wh[(size_t)l * HID * HID + c * HID + k] = h;
  Wl[(size_t)l * HID * HID + c * HID + k] = f2bf(w - bf2f(h));
}

// ---------------- generic W split+transpose for MLP weights: [K][C] -> hi/lo [C][K] ----------------
__global__ __launch_bounds__(256) void k_wsplit_t(const float* __restrict__ Win,
                                                  unsigned short* __restrict__ Wth,
                                                  unsigned short* __restrict__ Wtl, int K, int C) {
  int idx = blockIdx.x * 256 + threadIdx.x;
  if (idx < K * C) {
    int k = idx / C, c = idx - k * C;
    float w = Win[idx];
    unsigned short h = f2bf(w);
    Wth[(size_t)c * K + k] = h;
    Wtl[(size_t)c * K + k] = f2bf(w - bf2f(h));
  }
}

// ---------------- aggregation layers 2-4 (prescaled bf16 gather, fp32 accumulate) ----------------
__global__ __launch_bounds__(256) void k_agg(const unsigned short* __restrict__ xb, const int* __restrict__ row_ptr,
                                             const int* __restrict__ csr_src, const float* __restrict__ norm_dst,
                                             unsigned short* __restrict__ agg_hi, unsigned short* __restrict__ agg_lo) {
  int node = blockIdx.x * 16 + (threadIdx.x >> 4);
  int l16 = threadIdx.x & 15;
  if (node >= N_NODES) return;
  int s0 = row_ptr[node], s1 = row_ptr[node + 1];
  float acc[8];
#pragma unroll
  for (int j = 0; j < 8; ++j) acc[j] = 0.f;
  int i = s0;
  for (; i + 7 < s1; i += 8) {
    uint4 u[8];
#pragma unroll
    for (int e = 0; e < 8; ++e)
      u[e] = *(const uint4*)(xb + (size_t)csr_src[i + e] * HID + l16 * 8);
#pragma unroll
    for (int e = 0; e < 8; ++e) {
      unsigned uu[4] = {u[e].x, u[e].y, u[e].z, u[e].w};
#pragma unroll
      for (int q = 0; q < 4; ++q) {
        union { unsigned u; float f; } lo{uu[q] << 16}, hi{uu[q] & 0xffff0000u};
        acc[q * 2 + 0] += lo.f;
        acc[q * 2 + 1] += hi.f;
      }
    }
  }
  for (; i + 3 < s1; i += 4) {
    uint4 u[4];
#pragma unroll
    for (int e = 0; e < 4; ++e)
      u[e] = *(const uint4*)(xb + (size_t)csr_src[i + e] * HID + l16 * 8);
#pragma unroll
    for (int e = 0; e < 4; ++e) {
      unsigned uu[4] = {u[e].x, u[e].y, u[e].z, u[e].w};
#pragma unroll
      for (int q = 0; q < 4; ++q) {
        union { unsigned u; float f; } lo{uu[q] << 16}, hi{uu[q] & 0xffff0000u};
        acc[q * 2 + 0] += lo.f;
        acc[q * 2 + 1] += hi.f;
      }
    }
  }
  for (; i < s1; ++i) {
    uint4 u = *(const uint4*)(xb + (size_t)csr_src[i] * HID + l16 * 8);
    unsigned uu[4] = {u.x, u.y, u.z, u.w};
#pragma unroll
    for (int q = 0; q < 4; ++q) {
      union { unsigned u; float f; } lo{uu[q] << 16}, hi{uu[q] & 0xffff0000u};
      acc[q * 2 + 0] += lo.f;
      acc[q * 2 + 1] += hi.f;
    }
  }
  float nd = norm_dst[node];
  unsigned short hh[8], ll[8];
#pragma unroll
  for (int j = 0; j < 8; ++j) {
    float v = acc[j] * nd;
    hh[j] = f2bf(v);
    ll[j] = f2bf(v - bf2f(hh[j]));
  }
  uint4 ho, lo4;
  ho.x = (unsigned)hh[0] | ((unsigned)hh[1] << 16); ho.y = (unsigned)hh[2] | ((unsigned)hh[3] << 16);
  ho.z = (unsigned)hh[4] | ((unsigned)hh[5] << 16); ho.w = (unsigned)hh[6] | ((unsigned)hh[7] << 16);
  lo4.x = (unsigned)ll[0] | ((unsigned)ll[1] << 16); lo4.y = (unsigned)ll[2] | ((unsigned)ll[3] << 16);
  lo4.z = (unsigned)ll[4] | ((unsigned)ll[5] << 16); lo4.w = (unsigned)ll[6] | ((unsigned)ll[7] << 16);
  *(uint4*)(agg_hi + (size_t)node * HID + l16 * 8) = ho;
  *(uint4*)(agg_lo + (size_t)node * HID + l16 * 8) = lo4;
}

// ---------------- MFMA GEMM: Y = A@W + b, bf16x3 (fp32-grade), fused BN stats; Yb output bf16 ----------------
__global__ __launch_bounds__(256, 4) void k_gemm_mfma(const unsigned short* __restrict__ Ah,
                                                      const unsigned short* __restrict__ Al,
                                                      const unsigned short* __restrict__ Bh,
                                                      const unsigned short* __restrict__ Bl,
                                                      const float* __restrict__ bias,
                                                      unsigned short* __restrict__ Y16,
                                                      float* __restrict__ sums, float* __restrict__ sumsq) {
  __shared__ unsigned short sAh[128 * LSTR], sAl[128 * LSTR], sBh[128 * LSTR], sBl[128 * LSTR];  // 40960 B
  const int tid = threadIdx.x;
  const int lane = tid & 63, wid = tid >> 6;
  const int l15 = lane & 15, kg = lane >> 4;
  const int row0 = blockIdx.x * 128;

  f32x4 acc[2][8];
#pragma unroll
  for (int mi = 0; mi < 2; ++mi)
#pragma unroll
    for (int ni = 0; ni < 8; ++ni) acc[mi][ni] = (f32x4){0.f, 0.f, 0.f, 0.f};

  for (int kb = 0; kb < 4; ++kb) {
    const int k0 = kb * 32;
#pragma unroll
    for (int it = 0; it < 2; ++it) {
      int idx = tid * 2 + it;
      int r = idx >> 2, q = idx & 3;
      int gr = row0 + r;
      s16x8 vh = {0, 0, 0, 0, 0, 0, 0, 0}, vl = {0, 0, 0, 0, 0, 0, 0, 0};
      if (gr < N_NODES) {
        vh = *(const s16x8*)(Ah + (size_t)gr * HID + k0 + q * 8);
        vl = *(const s16x8*)(Al + (size_t)gr * HID + k0 + q * 8);
      }
      *(s16x8*)&sAh[r * LSTR + q * 8] = vh;
      *(s16x8*)&sAl[r * LSTR + q * 8] = vl;
      *(s16x8*)&sBh[r * LSTR + q * 8] = *(const s16x8*)(Bh + (size_t)r * HID + k0 + q * 8);
      *(s16x8*)&sBl[r * LSTR + q * 8] = *(const s16x8*)(Bl + (size_t)r * HID + k0 + q * 8);
    }
    __syncthreads();
    s16x8 afh[2], afl[2];
#pragma unroll
    for (int mi = 0; mi < 2; ++mi) {
      int ar = wid * 32 + mi * 16 + l15;
      afh[mi] = *(const s16x8*)&sAh[ar * LSTR + kg * 8];
      afl[mi] = *(const s16x8*)&sAl[ar * LSTR + kg * 8];
    }
#pragma unroll
    for (int ni = 0; ni < 8; ++ni) {
      int bc = ni * 16 + l15;
      s16x8 bh = *(const s16x8*)&sBh[bc * LSTR + kg * 8];
      s16x8 bl = *(const s16x8*)&sBl[bc * LSTR + kg * 8];
#pragma unroll
      for (int mi = 0; mi < 2; ++mi) {
        acc[mi][ni] = __builtin_amdgcn_mfma_f32_16x16x32_bf16(afh[mi], bh, acc[mi][ni], 0, 0, 0);
        acc[mi][ni] = __builtin_amdgcn_mfma_f32_16x16x32_bf16(afh[mi], bl, acc[mi][ni], 0, 0, 0);
        acc[mi][ni] = __builtin_amdgcn_mfma_f32_16x16x32_bf16(afl[mi], bh, acc[mi][ni], 0, 0, 0);
      }
    }
    __syncthreads();
  }

  float bv[8], sp[8], qp[8];
#pragma unroll
  for (int ni = 0; ni < 8; ++ni) {
    bv[ni] = bias[ni * 16 + l15];
    sp[ni] = 0.f; qp[ni] = 0.f;
  }
#pragma unroll
  for (int mi = 0; mi < 2; ++mi) {
    int rbase = row0 + wid * 32 + mi * 16 + kg * 4;
#pragma unroll
    for (int reg = 0; reg < 4; ++reg) {
      int r = rbase + reg;
      if (r < N_NODES) {
        unsigned short* yr = Y16 + (size_t)r * HID;
#pragma unroll
        for (int ni = 0; ni < 8; ++ni) {
          float y = acc[mi][ni][reg] + bv[ni];
          yr[ni * 16 + l15] = f2bf(y);
          sp[ni] += y;
          qp[ni] += y * y;
        }
      }
    }
  }
  __syncthreads();
  float* red_s = (float*)sAh;  // [16][128] = 8KB
  float* red_q = (float*)sBh;
  int slot = wid * 4 + kg;
#pragma unroll
  for (int ni = 0; ni < 8; ++ni) {
    red_s[slot * 128 + ni * 16 + l15] = sp[ni];
    red_q[slot * 128 + ni * 16 + l15] = qp[ni];
  }
  __syncthreads();
  if (tid < 128) {
    float a = 0.f, b2 = 0.f;
#pragma unroll
    for (int s = 0; s < 16; ++s) {
      a += red_s[s * 128 + tid];
      b2 += red_q[s * 128 + tid];
    }
    atomicAdd(&sums[tid], a);
    atomicAdd(&sumsq[tid], b2);
  }
}

// ---------------- BN apply + relu + residual (scale/shift derived in-block); writes x + xb ----------------
__global__ __launch_bounds__(256) void k_bn_apply(const unsigned short* __restrict__ Y16,
                                                  const float* __restrict__ sums, const float* __restrict__ sumsq,
                                                  const float* __restrict__ gamma, const float* __restrict__ beta,
                                                  const float* __restrict__ norm_src,
                                                  float* __restrict__ x, unsigned short* __restrict__ xb) {
  __shared__ float scs[128], shs[128];
  int tid = threadIdx.x;
  if (tid < 128) {
    float mu = sums[tid] / (float)N_NODES;
    float var = sumsq[tid] / (float)N_NODES - mu * mu;
    float sc = gamma[tid] * rsqrtf(var + EPSV);
    scs[tid] = sc;
    shs[tid] = beta[tid] - mu * sc;
  }
  __syncthreads();
  int i = blockIdx.x * 256 + tid;  // over N*16 chunks of 8 cols
  const int total = N_NODES * (HID / 8);
  if (i >= total) return;
  int c8 = i & 15, r = i >> 4;
  uint4 yu = *(const uint4*)(Y16 + (size_t)r * HID + c8 * 8);
  unsigned yw[4] = {yu.x, yu.y, yu.z, yu.w};
  float y[8];
#pragma unroll
  for (int q = 0; q < 4; ++q) {
    union { unsigned u; float f; } lo{yw[q] << 16}, hi{yw[q] & 0xffff0000u};
    y[q * 2 + 0] = lo.f;
    y[q * 2 + 1] = hi.f;
  }
  float* xr = x + (size_t)r * HID + c8 * 8;
  float4 x0 = *(const float4*)xr;
  float4 x1 = *(const float4*)(xr + 4);
  float xv[8] = {x0.x, x0.y, x0.z, x0.w, x1.x, x1.y, x1.z, x1.w};
  float o[8];
#pragma unroll
  for (int q = 0; q < 8; ++q)
    o[q] = fmaxf(y[q] * scs[c8 * 8 + q] + shs[c8 * 8 + q], 0.f) + xv[q];
  *(float4*)xr = make_float4(o[0], o[1], o[2], o[3]);
  *(float4*)(xr + 4) = make_float4(o[4], o[5], o[6], o[7]);
  float ns = norm_src[r];
  uint4 p;
  p.x = (unsigned)f2bf(o[0] * ns) | ((unsigned)f2bf(o[1] * ns) << 16);
  p.y = (unsigned)f2bf(o[2] * ns) | ((unsigned)f2bf(o[3] * ns) << 16);
  p.z = (unsigned)f2bf(o[4] * ns) | ((unsigned)f2bf(o[5] * ns) << 16);
  p.w = (unsigned)f2bf(o[6] * ns) | ((unsigned)f2bf(o[7] * ns) << 16);
  *(uint4*)(xb + (size_t)r * HID + c8 * 8) = p;
}

// ---------------- MFMA readout: BN(l=3, in-block) + residual -> 128->64->32->6 ----------------
__global__ __launch_bounds__(256, 4) void k_readout(const unsigned short* __restrict__ Y16,
                                                    const float* __restrict__ Xres,
                                                    const float* __restrict__ sums, const float* __restrict__ sumsq,
                                                    const float* __restrict__ gamma, const float* __restrict__ beta,
                                                    const unsigned short* __restrict__ B1h, const unsigned short* __restrict__ B1l,
                                                    const float* __restrict__ b1,
                                                    const unsigned short* __restrict__ B2h, const unsigned short* __restrict__ B2l,
                                                    const float* __restrict__ b2,
                                                    const float* __restrict__ W3, const float* __restrict__ b3,
                                                    float* __restrict__ out) {
  __shared__ unsigned short sAh[128 * 72], sAl[128 * 72];  // 36864 B
  __shared__ float scs[128], shs[128];
  __shared__ float Ws3s[192];
  const int tid = threadIdx.x;
  const int lane = tid & 63, wid = tid >> 6;
  const int l15 = lane & 15, kg = lane >> 4;
  const int row0 = blockIdx.x * 128;
  if (tid < 128) {
    float mu = sums[tid] / (float)N_NODES;
    float var = sumsq[tid] / (float)N_NODES - mu * mu;
    float sc = gamma[tid] * rsqrtf(var + EPSV);
    scs[tid] = sc;
    shs[tid] = beta[tid] - mu * sc;
  }
  if (tid < 192) Ws3s[tid] = W3[tid];
  __syncthreads();

  f32x4 acc1[2][4];
#pragma unroll
  for (int mi = 0; mi < 2; ++mi)
#pragma unroll
    for (int ni = 0; ni < 4; ++ni) acc1[mi][ni] = (f32x4){0.f, 0.f, 0.f, 0.f};

  for (int slab = 0; slab < 2; ++slab) {
    const int c0 = slab * 64;
#pragma unroll
    for (int it = 0; it < 4; ++it) {
      int idx = tid + it * 256;        // 0..1023
      int r = idx >> 3, q = idx & 7;   // row, 8-col chunk
      int gr = row0 + r;
      float v[8];
      if (gr < N_NODES) {
        uint4 yu = *(const uint4*)(Y16 + (size_t)gr * HID + c0 + q * 8);
        unsigned yw[4] = {yu.x, yu.y, yu.z, yu.w};
        const float* xp = Xres + (size_t)gr * HID + c0 + q * 8;
        float4 x0 = *(const float4*)xp, x1 = *(const float4*)(xp + 4);
        float xvv[8] = {x0.x, x0.y, x0.z, x0.w, x1.x, x1.y, x1.z, x1.w};
        const float* scp = &scs[c0 + q * 8];
        const float* shp = &shs[c0 + q * 8];
#pragma unroll
        for (int qq = 0; qq < 4; ++qq) {
          union { unsigned u; float f; } lo{yw[qq] << 16}, hi{yw[qq] & 0xffff0000u};
          v[qq * 2 + 0] = fmaxf(lo.f * scp[qq * 2 + 0] + shp[qq * 2 + 0], 0.f) + xvv[qq * 2 + 0];
          v[qq * 2 + 1] = fmaxf(hi.f * scp[qq * 2 + 1] + shp[qq * 2 + 1], 0.f) + xvv[qq * 2 + 1];
        }
      } else {
#pragma unroll
        for (int j = 0; j < 8; ++j) v[j] = 0.f;
      }
      short hh[8], ll[8];
#pragma unroll
      for (int j = 0; j < 8; ++j) {
        unsigned short hb = f2bf(v[j]);
        hh[j] = (short)hb;
        ll[j] = (short)f2bf(v[j] - bf2f(hb));
      }
      *(s16x8*)&sAh[r * 72 + q * 8] = (s16x8){hh[0], hh[1], hh[2], hh[3], hh[4], hh[5], hh[6], hh[7]};
      *(s16x8*)&sAl[r * 72 + q * 8] = (s16x8){ll[0], ll[1], ll[2], ll[3], ll[4], ll[5], ll[6], ll[7]};
    }
    __syncthreads();
#pragma unroll
    for (int kb = 0; kb < 2; ++kb) {
      s16x8 afh[2], afl[2];
#pragma unroll
      for (int mi = 0; mi < 2; ++mi) {
        int ar = wid * 32 + mi * 16 + l15;
        afh[mi] = *(const s16x8*)&sAh[ar * 72 + kb * 32 + kg * 8];
        afl[mi] = *(const s16x8*)&sAl[ar * 72 + kb * 32 + kg * 8];
      }
#pragma unroll
      for (int ni = 0; ni < 4; ++ni) {
        int bc = ni * 16 + l15;
        s16x8 bh = *(const s16x8*)(B1h + (size_t)bc * 128 + c0 + kb * 32 + kg * 8);
        s16x8 bl = *(const s16x8*)(B1l + (size_t)bc * 128 + c0 + kb * 32 + kg * 8);
#pragma unroll
        for (int mi = 0; mi < 2; ++mi) {
          acc1[mi][ni] = __builtin_amdgcn_mfma_f32_16x16x32_bf16(afh[mi], bh, acc1[mi][ni], 0, 0, 0);
          acc1[mi][ni] = __builtin_amdgcn_mfma_f32_16x16x32_bf16(afh[mi], bl, acc1[mi][ni], 0, 0, 0);
          acc1[mi][ni] = __builtin_amdgcn_mfma_f32_16x16x32_bf16(afl[mi], bh, acc1[mi][ni], 0, 0, 0);
        }
      }
    }
    __syncthreads();
  }

  float bv1[4];
#pragma unroll
  for (int ni = 0; ni < 4; ++ni) bv1[ni] = b1[ni * 16 + l15];
#pragma unroll
  for (int mi = 0; mi < 2; ++mi)
#pragma unroll
    for (int ni = 0; ni < 4; ++ni)
#pragma unroll
      for (int reg = 0; reg < 4; ++reg) {
        int rr = wid * 32 + mi * 16 + kg * 4 + reg;
        float v = fmaxf(acc1[mi][ni][reg] + bv1[ni], 0.f);
        unsigned short hb = f2bf(v);
        sAh[rr * 72 + ni * 16 + l15] = hb;
        sAl[rr * 72 + ni * 16 + l15] = f2bf(v - bf2f(hb));
      }
  __syncthreads();

  f32x4 acc2[2][2];
#pragma unroll
  for (int mi = 0; mi < 2; ++mi)
#pragma unroll
    for (int ni = 0; ni < 2; ++ni) acc2[mi][ni] = (f32x4){0.f, 0.f, 0.f, 0.f};
#pragma unroll
  for (int kb = 0; kb < 2; ++kb) {
    s16x8 afh[2], afl[2];
#pragma unroll
    for (int mi = 0; mi < 2; ++mi) {
      int ar = wid * 32 + mi * 16 + l15;
      afh[mi] = *(const s16x8*)&sAh[ar * 72 + kb * 32 + kg * 8];
      afl[mi] = *(const s16x8*)&sAl[ar * 72 + kb * 32 + kg * 8];
    }
#pragma unroll
    for (int ni = 0; ni < 2; ++ni) {
      int bc = ni * 16 + l15;
      s16x8 bh = *(const s16x8*)(B2h + (size_t)bc * 64 + kb * 32 + kg * 8);
      s16x8 bl = *(const s16x8*)(B2l + (size_t)bc * 64 + kb * 32 + kg * 8);
#pragma unroll
      for (int mi = 0; mi < 2; ++mi) {
        acc2[mi][ni] = __builtin_amdgcn_mfma_f32_16x16x32_bf16(afh[mi], bh, acc2[mi][ni], 0, 0, 0);
        acc2[mi][ni] = __builtin_amdgcn_mfma_f32_16x16x32_bf16(afh[mi], bl, acc2[mi][ni], 0, 0, 0);
        acc2[mi][ni] = __builtin_amdgcn_mfma_f32_16x16x32_bf16(afl[mi], bh, acc2[mi][ni], 0, 0, 0);
      }
    }
  }
  __syncthreads();

  float* h2s = (float*)sAh;
  float bv2[2];
#pragma unroll
  for (int ni = 0; ni < 2; ++ni) bv2[ni] = b2[ni * 16 + l15];
#pragma unroll
  for (int mi = 0; mi < 2; ++mi)
#pragma unroll
    for (int ni = 0; ni < 2; ++ni)
#pragma unroll
      for (int reg = 0; reg < 4; ++reg) {
        int rr = wid * 32 + mi * 16 + kg * 4 + reg;
        h2s[rr * 36 + ni * 16 + l15] = fmaxf(acc2[mi][ni][reg] + bv2[ni], 0.f);
      }
  __syncthreads();

  if (tid < 128) {
    int gr = row0 + tid;
    if (gr < N_NODES) {
      float h2r[32];
#pragma unroll
      for (int q = 0; q < 8; ++q) {
        float4 t = *(const float4*)&h2s[tid * 36 + q * 4];
        h2r[q * 4 + 0] = t.x; h2r[q * 4 + 1] = t.y; h2r[q * 4 + 2] = t.z; h2r[q * 4 + 3] = t.w;
      }
      float p[6];
#pragma unroll
      for (int o = 0; o < 6; ++o) p[o] = b3[o];
#pragma unroll
      for (int k = 0; k < 32; ++k)
#pragma unroll
        for (int o = 0; o < 6; ++o) p[o] += h2r[k] * Ws3s[k * 6 + o];
      float* orow = out + (size_t)gr * 6;
#pragma unroll
      for (int o = 0; o < 6; ++o) orow[o] = p[o];
    }
  }
}

extern "C" void kernel_launch(void* const* d_in, const int* in_sizes, int n_in,
                              void* d_out, int out_size, void* d_ws, size_t ws_size,
                              hipStream_t stream) {
  const int* h = (const int*)d_in[0];
  const int* src = (const int*)d_in[1];
  const int* dst = (const int*)d_in[2];
  const float* emb = (const float*)d_in[3];
  const float* W = (const float*)d_in[4];
  const float* b = (const float*)d_in[5];
  const float* gamma = (const float*)d_in[6];
  const float* beta = (const float*)d_in[7];
  const float* W1 = (const float*)d_in[8];
  const float* b1 = (const float*)d_in[9];
  const float* W2 = (const float*)d_in[10];
  const float* b2 = (const float*)d_in[11];
  const float* W3 = (const float*)d_in[12];
  const float* b3 = (const float*)d_in[13];
  float* out = (float*)d_out;

  char* ws = (char*)d_ws;
  size_t off = 0;
  auto alloc = [&](size_t bytes) -> void* {
    void* p = ws + off;
    off += (bytes + 255) & ~(size_t)255;
    return p;
  };
  float* norm_src = (float*)alloc(N_NODES * 4);
  float* norm_dst = (float*)alloc(N_NODES * 4);
  int* row_ptr = (int*)alloc((N_NODES + 1) * 4);
  int* csr_src = (int*)alloc((size_t)N_EDGES * 4);
  int* bucket_cnt_d = (int*)alloc(NBUCK * 4);
  int* bucket_base_d = (int*)alloc((NBUCK + 1) * 4);
  int* bucket_fill_d = (int*)alloc(NBUCK * 4);
  int* bucket_cnt_s = (int*)alloc(NBUCK * 4);
  int* bucket_base_s = (int*)alloc((NBUCK + 1) * 4);
  int* bucket_fill_s = (int*)alloc(NBUCK * 4);
  float* x = (float*)alloc((size_t)N_NODES * HID * 4);
  unsigned short* xb = (unsigned short*)alloc((size_t)N_NODES * HID * 2);
  unsigned short* agg_hi = (unsigned short*)alloc((size_t)N_NODES * HID * 2);
  unsigned short* agg_lo = (unsigned short*)alloc((size_t)N_NODES * HID * 2);
  unsigned short* Yb16 = (unsigned short*)alloc((size_t)N_NODES * HID * 2);
  unsigned short* Wh = (unsigned short*)alloc((size_t)N_LAYERS * HID * HID * 2);
  unsigned short* Wl = (unsigned short*)alloc((size_t)N_LAYERS * HID * HID * 2);
  unsigned short* B1h = (unsigned short*)alloc(64 * 128 * 2);
  unsigned short* B1l = (unsigned short*)alloc(64 * 128 * 2);
  unsigned short* B2h = (unsigned short*)alloc(32 * 64 * 2);
  unsigned short* B2l = (unsigned short*)alloc(32 * 64 * 2);
  float* sums = (float*)alloc(512);
  float* sumsq = (float*)alloc(512);
  int2* pairs = (int2*)alloc((size_t)N_EDGES * 8);  // 12.8MB
  int* svals = (int*)alloc((size_t)N_EDGES * 4);    // 6.4MB

  hipMemsetAsync(bucket_cnt_d, 0, NBUCK * 4, stream);
  hipMemsetAsync(bucket_cnt_s, 0, NBUCK * 4, stream);
  k_hist2<<<1024, 256, 0, stream>>>(src, dst, bucket_cnt_d, bucket_cnt_s);
  k_bscan<<<1, 256, 0, stream>>>(bucket_cnt_d, bucket_base_d, bucket_fill_d);
  k_bscan<<<1, 256, 0, stream>>>(bucket_cnt_s, bucket_base_s, bucket_fill_s);
  k_scatter2<<<(N_EDGES + CBLK - 1) / CBLK, 256, 0, stream>>>(src, dst, bucket_base_d, bucket_fill_d, pairs);
  k_scatter_src<<<(N_EDGES + CBLK - 1) / CBLK, 256, 0, stream>>>(src, bucket_base_s, bucket_fill_s, svals);
  k_bucket_csr<<<NBUCK, 256, 0, stream>>>(pairs, bucket_base_d, row_ptr, norm_dst, csr_src);
  k_src_count<<<NBUCK, 256, 0, stream>>>(svals, bucket_base_s, norm_src);
  k_embed<<<(N_NODES * (HID / 4) + 255) / 256, 256, 0, stream>>>(h, emb, x);
  k_wsplit<<<N_LAYERS * 128, 128, 0, stream>>>(W, Wh, Wl);
  k_wsplit_t<<<(128 * 64 + 255) / 256, 256, 0, stream>>>(W1, B1h, B1l, 128, 64);
  k_wsplit_t<<<(64 * 32 + 255) / 256, 256, 0, stream>>>(W2, B2h, B2l, 64, 32);

  for (int l = 0; l < N_LAYERS; ++l) {
    if (l == 0) {
      k_agg1<<<(N_NODES + 63) / 64, 256, 0, stream>>>(row_ptr, csr_src, h, norm_src, norm_dst, emb,
                                                      agg_hi, agg_lo);
    } else {
      k_agg<<<(N_NODES + 15) / 16, 256, 0, stream>>>(xb, row_ptr, csr_src, norm_dst, agg_hi, agg_lo);
    }
    hipMemsetAsync(sums, 0, 1024, stream);  // sums+sumsq contiguous
    k_gemm_mfma<<<(N_NODES + 127) / 128, 256, 0, stream>>>(agg_hi, agg_lo,
                                                           Wh + (size_t)l * HID * HID, Wl + (size_t)l * HID * HID,
                                                           b + l * HID, Yb16, sums, sumsq);
    if (l < N_LAYERS - 1) {
      k_bn_apply<<<(N_NODES * (HID / 8) + 255) / 256, 256, 0, stream>>>(Yb16, sums, sumsq,
                                                                        gamma + l * HID, beta + l * HID,
                                                                        norm_src, x, xb);
    }
  }
  k_readout<<<(N_NODES + 127) / 128, 256, 0, stream>>>(Yb16, x, sums, sumsq,
                                                       gamma + 3 * HID, beta + 3 * HID,
                                                       B1h, B1l, b1, B2h, B2l, b2, W3, b3, out);
}

// Round 18
// 564.696 us; speedup vs baseline: 1.2023x; 1.0924x over previous
//
#include <hip/hip_runtime.h>

#define N_NODES 100000
#define N_EDGES 1600000
#define HID 128
#define N_LAYERS 4
#define EPSV 1e-5f
#define NBUCK 1024
#define BSHIFT 7      // 128 nodes per bucket
#define CBLK 4096     // edges per scatter block
#define VOCAB 7
#define LSTR 40       // LDS row stride in shorts (80B: 16B-aligned, 2-way-max bank conflicts = free)

using f32x4 = __attribute__((ext_vector_type(4))) float;
using s16x8 = __attribute__((ext_vector_type(8))) short;

__device__ __forceinline__ unsigned short f2bf(float f) {
  union { float f; unsigned u; } c{f};
  unsigned u = c.u;
  return (unsigned short)((u + 0x7fffu + ((u >> 16) & 1u)) >> 16);
}
__device__ __forceinline__ float bf2f(unsigned short s) {
  union { unsigned u; float f; } c{(unsigned)s << 16};
  return c.f;
}

// ---------------- Pass A: dst-bucket AND src-bucket histograms in one pass ----------------
__global__ __launch_bounds__(256) void k_hist2(const int* __restrict__ src, const int* __restrict__ dst,
                                               int* __restrict__ bucket_cnt_d, int* __restrict__ bucket_cnt_s) {
  __shared__ int hd[NBUCK];
  __shared__ int hs[NBUCK];
  for (int i = threadIdx.x; i < NBUCK; i += 256) { hd[i] = 0; hs[i] = 0; }
  __syncthreads();
  int per = (N_EDGES + gridDim.x - 1) / gridDim.x;
  int lo = blockIdx.x * per;
  int hi = lo + per; if (hi > N_EDGES) hi = N_EDGES;
  for (int i = lo + threadIdx.x; i < hi; i += 256) {
    atomicAdd(&hd[dst[i] >> BSHIFT], 1);
    atomicAdd(&hs[src[i] >> BSHIFT], 1);
  }
  __syncthreads();
  for (int i = threadIdx.x; i < NBUCK; i += 256) {
    if (hd[i]) atomicAdd(&bucket_cnt_d[i], hd[i]);
    if (hs[i]) atomicAdd(&bucket_cnt_s[i], hs[i]);
  }
}

// ---------------- Pass B: scan 1024 bucket counts; zero fill ----------------
__global__ __launch_bounds__(256) void k_bscan(const int* __restrict__ cnt, int* __restrict__ base,
                                               int* __restrict__ fill) {
  __shared__ int wsum[4];
  int tid = threadIdx.x;
  int4 v = *(const int4*)(cnt + tid * 4);
  int s4 = v.x + v.y + v.z + v.w;
  int lane = tid & 63, wid = tid >> 6;
  int sc = s4;
#pragma unroll
  for (int off = 1; off < 64; off <<= 1) {
    int u = __shfl_up(sc, off, 64);
    if (lane >= off) sc += u;
  }
  if (lane == 63) wsum[wid] = sc;
  __syncthreads();
  int woff = 0;
#pragma unroll
  for (int w = 0; w < 4; ++w) woff += (w < wid) ? wsum[w] : 0;
  int excl = woff + sc - s4;
  int4 o;
  o.x = excl; o.y = o.x + v.x; o.z = o.y + v.y; o.w = o.z + v.z;
  *(int4*)(base + tid * 4) = o;
  *(int4*)(fill + tid * 4) = make_int4(0, 0, 0, 0);
  if (tid == 255) base[NBUCK] = woff + sc;  // == N_EDGES
}

// ---------------- Pass C: block-local staged scatter of (src,dst) pairs by dst bucket ----------------
__global__ __launch_bounds__(256) void k_scatter2(const int* __restrict__ src, const int* __restrict__ dst,
                                                  const int* __restrict__ bucket_base, int* __restrict__ bucket_fill,
                                                  int2* __restrict__ pairs) {
  __shared__ int hist[NBUCK];
  __shared__ int loff[NBUCK];
  __shared__ int gbase_s[NBUCK];
  __shared__ int lcur[NBUCK];
  __shared__ int wsum[4];
  __shared__ int2 stage[CBLK];                 // 32 KB
  __shared__ unsigned short sbuck[CBLK];       // 8 KB
  int tid = threadIdx.x;
  int e0 = blockIdx.x * CBLK;
  int e1 = e0 + CBLK; if (e1 > N_EDGES) e1 = N_EDGES;
  int n = e1 - e0;
  for (int i = tid; i < NBUCK; i += 256) hist[i] = 0;
  __syncthreads();
  int2 ev[CBLK / 256];
  int nb[CBLK / 256];
#pragma unroll
  for (int j = 0; j < CBLK / 256; ++j) {
    int idx = e0 + j * 256 + tid;
    nb[j] = -1;
    if (idx < e1) {
      ev[j] = make_int2(src[idx], dst[idx]);
      nb[j] = ev[j].y >> BSHIFT;
      atomicAdd(&hist[nb[j]], 1);
    }
  }
  __syncthreads();
  int4 hv = *(const int4*)(hist + tid * 4);
  int s4 = hv.x + hv.y + hv.z + hv.w;
  int lane = tid & 63, wid = tid >> 6;
  int sc = s4;
#pragma unroll
  for (int off = 1; off < 64; off <<= 1) {
    int u = __shfl_up(sc, off, 64);
    if (lane >= off) sc += u;
  }
  if (lane == 63) wsum[wid] = sc;
  __syncthreads();
  int woff = 0;
#pragma unroll
  for (int w = 0; w < 4; ++w) woff += (w < wid) ? wsum[w] : 0;
  int excl = woff + sc - s4;
  loff[tid * 4 + 0] = excl;
  loff[tid * 4 + 1] = excl + hv.x;
  loff[tid * 4 + 2] = excl + hv.x + hv.y;
  loff[tid * 4 + 3] = excl + hv.x + hv.y + hv.z;
  __syncthreads();
  for (int b = tid; b < NBUCK; b += 256) {
    int c = hist[b];
    if (c > 0) gbase_s[b] = bucket_base[b] + atomicAdd(&bucket_fill[b], c);
    lcur[b] = loff[b];
  }
  __syncthreads();
#pragma unroll
  for (int j = 0; j < CBLK / 256; ++j) {
    if (nb[j] >= 0) {
      int p = atomicAdd(&lcur[nb[j]], 1);
      stage[p] = ev[j];
      sbuck[p] = (unsigned short)nb[j];
    }
  }
  __syncthreads();
  for (int s = tid; s < n; s += 256) {
    int b = sbuck[s];
    pairs[gbase_s[b] + (s - loff[b])] = stage[s];
  }
}

// ---------------- Pass C': block-local staged scatter of src values by src bucket ----------------
__global__ __launch_bounds__(256) void k_scatter_src(const int* __restrict__ src,
                                                     const int* __restrict__ base_s, int* __restrict__ fill_s,
                                                     int* __restrict__ svals) {
  __shared__ int hist[NBUCK];
  __shared__ int loff[NBUCK];
  __shared__ int gbase_s[NBUCK];
  __shared__ int lcur[NBUCK];
  __shared__ int wsum[4];
  __shared__ int stage[CBLK];                  // 16 KB
  __shared__ unsigned short sbuck[CBLK];       // 8 KB
  int tid = threadIdx.x;
  int e0 = blockIdx.x * CBLK;
  int e1 = e0 + CBLK; if (e1 > N_EDGES) e1 = N_EDGES;
  int n = e1 - e0;
  for (int i = tid; i < NBUCK; i += 256) hist[i] = 0;
  __syncthreads();
  int ev[CBLK / 256];
  int nb[CBLK / 256];
#pragma unroll
  for (int j = 0; j < CBLK / 256; ++j) {
    int idx = e0 + j * 256 + tid;
    nb[j] = -1;
    if (idx < e1) {
      ev[j] = src[idx];
      nb[j] = ev[j] >> BSHIFT;
      atomicAdd(&hist[nb[j]], 1);
    }
  }
  __syncthreads();
  int4 hv = *(const int4*)(hist + tid * 4);
  int s4 = hv.x + hv.y + hv.z + hv.w;
  int lane = tid & 63, wid = tid >> 6;
  int sc = s4;
#pragma unroll
  for (int off = 1; off < 64; off <<= 1) {
    int u = __shfl_up(sc, off, 64);
    if (lane >= off) sc += u;
  }
  if (lane == 63) wsum[wid] = sc;
  __syncthreads();
  int woff = 0;
#pragma unroll
  for (int w = 0; w < 4; ++w) woff += (w < wid) ? wsum[w] : 0;
  int excl = woff + sc - s4;
  loff[tid * 4 + 0] = excl;
  loff[tid * 4 + 1] = excl + hv.x;
  loff[tid * 4 + 2] = excl + hv.x + hv.y;
  loff[tid * 4 + 3] = excl + hv.x + hv.y + hv.z;
  __syncthreads();
  for (int b = tid; b < NBUCK; b += 256) {
    int c = hist[b];
    if (c > 0) gbase_s[b] = base_s[b] + atomicAdd(&fill_s[b], c);
    lcur[b] = loff[b];
  }
  __syncthreads();
#pragma unroll
  for (int j = 0; j < CBLK / 256; ++j) {
    if (nb[j] >= 0) {
      int p = atomicAdd(&lcur[nb[j]], 1);
      stage[p] = ev[j];
      sbuck[p] = (unsigned short)nb[j];
    }
  }
  __syncthreads();
  for (int s = tid; s < n; s += 256) {
    int b = sbuck[s];
    svals[gbase_s[b] + (s - loff[b])] = stage[s];
  }
}

// ---------------- Pass D': per-src-bucket count -> norm_src ----------------
__global__ __launch_bounds__(256) void k_src_count(const int* __restrict__ svals, const int* __restrict__ base_s,
                                                   float* __restrict__ norm_src) {
  __shared__ int hist[128];
  int bk = blockIdx.x;
  int b0 = base_s[bk], b1 = base_s[bk + 1];
  int tid = threadIdx.x;
  if (tid < 128) hist[tid] = 0;
  __syncthreads();
  for (int i = b0 + tid; i < b1; i += 256) atomicAdd(&hist[svals[i] & 127], 1);
  __syncthreads();
  if (tid < 128) {
    int g = (bk << BSHIFT) + tid;
    if (g < N_NODES) norm_src[g] = hist[tid] > 0 ? rsqrtf((float)hist[tid]) : 0.f;
  }
}

// ---------------- Pass D: per-bucket exact CSR (no global atomics) ----------------
__global__ __launch_bounds__(256) void k_bucket_csr(const int2* __restrict__ pairs, const int* __restrict__ base,
                                                    int* __restrict__ row_ptr, float* __restrict__ norm_dst,
                                                    int* __restrict__ csr_src) {
  __shared__ int hist[128];
  __shared__ int excl[129];
  __shared__ int curs[128];
  int bk = blockIdx.x;
  int b0 = base[bk], b1 = base[bk + 1];
  int tid = threadIdx.x;
  if (tid < 128) hist[tid] = 0;
  __syncthreads();
  for (int i = b0 + tid; i < b1; i += 256) atomicAdd(&hist[pairs[i].y & 127], 1);
  __syncthreads();
  if (tid < 128) {
    int v = hist[tid];
    int lane = tid & 63;
    int sc = v;
#pragma unroll
    for (int off = 1; off < 64; off <<= 1) {
      int u = __shfl_up(sc, off, 64);
      if (lane >= off) sc += u;
    }
    excl[tid] = sc - v;
    if (lane == 63 && tid < 64) excl[128] = sc;
  }
  __syncthreads();
  if (tid >= 64 && tid < 128) excl[tid] += excl[128];
  __syncthreads();
  int gbase = bk << BSHIFT;
  if (tid < 128) {
    int g = gbase + tid;
    if (g < N_NODES) {
      row_ptr[g] = b0 + excl[tid];
      norm_dst[g] = hist[tid] > 0 ? rsqrtf((float)hist[tid]) : 0.f;
    } else if (g == N_NODES) {
      row_ptr[N_NODES] = b0 + excl[tid];
    }
    curs[tid] = excl[tid];
  }
  __syncthreads();
  for (int i = b0 + tid; i < b1; i += 256) {
    int2 p = pairs[i];
    int pos = b0 + atomicAdd(&curs[p.y & 127], 1);
    csr_src[pos] = p.x;
  }
}

// ---------------- embedding lookup: writes x (fp32 residual only) ----------------
__global__ __launch_bounds__(256) void k_embed(const int* __restrict__ h, const float* __restrict__ emb,
                                               float* __restrict__ x) {
  int i = blockIdx.x * 256 + threadIdx.x;  // over N*32 float4
  const int total = N_NODES * (HID / 4);
  if (i < total) {
    int r = i >> 5, c = i & 31;
    ((float4*)x)[i] = ((const float4*)emb)[h[r] * (HID / 4) + c];
  }
}

// ---------------- layer-1 aggregation via class weights (VOCAB=7 trick); bf16 A output ----------------
__global__ __launch_bounds__(256) void k_agg1(const int* __restrict__ row_ptr, const int* __restrict__ csr_src,
                                              const int* __restrict__ h, const float* __restrict__ norm_src,
                                              const float* __restrict__ norm_dst, const float* __restrict__ emb,
                                              unsigned short* __restrict__ agg_hi) {
  __shared__ float embs[VOCAB * HID];  // 3.5 KB
  int tid = threadIdx.x;
  for (int i = tid; i < VOCAB * HID; i += 256) embs[i] = emb[i];
  __syncthreads();
  int node = blockIdx.x * 64 + (tid >> 2);
  int l4 = tid & 3;
  if (node >= N_NODES) return;
  int s0 = row_ptr[node], s1 = row_ptr[node + 1];
  float cw[VOCAB];
#pragma unroll
  for (int v = 0; v < VOCAB; ++v) cw[v] = 0.f;
  for (int i = s0 + l4; i < s1; i += 4) {
    int s = csr_src[i];
    int v = h[s];
    float ns = norm_src[s];
#pragma unroll
    for (int vv = 0; vv < VOCAB; ++vv) cw[vv] += (v == vv) ? ns : 0.f;
  }
#pragma unroll
  for (int v = 0; v < VOCAB; ++v) {
    cw[v] += __shfl_xor(cw[v], 1, 64);
    cw[v] += __shfl_xor(cw[v], 2, 64);
  }
  float nd = norm_dst[node];
  unsigned short* oh = agg_hi + (size_t)node * HID + l4 * 32;
#pragma unroll
  for (int q = 0; q < 4; ++q) {  // 8 cols per chunk
    unsigned short hh[8];
#pragma unroll
    for (int c = 0; c < 8; ++c) {
      int col = l4 * 32 + q * 8 + c;
      float s = 0.f;
#pragma unroll
      for (int v = 0; v < VOCAB; ++v) s += cw[v] * embs[v * HID + col];
      hh[c] = f2bf(s * nd);
    }
    uint4 ho;
    ho.x = (unsigned)hh[0] | ((unsigned)hh[1] << 16); ho.y = (unsigned)hh[2] | ((unsigned)hh[3] << 16);
    ho.z = (unsigned)hh[4] | ((unsigned)hh[5] << 16); ho.w = (unsigned)hh[6] | ((unsigned)hh[7] << 16);
    *(uint4*)(oh + q * 8) = ho;
  }
}

// ---------------- W split+transpose: Wt[l][col][k] hi/lo bf16 (GCN layers) ----------------
__global__ __launch_bounds__(128) void k_wsplit(const float* __restrict__ W, unsigned short* __restrict__ Wh,
                                                unsigned short* __restrict__ Wl) {
  int l = blockIdx.x >> 7, k = blockIdx.x & 127;
  int c = threadIdx.x;
  float w = W[(size_t)l * HID * HID + k * HID + c];
  unsigned short h = f2bf(w);
  Wh[(size_t)l * HID * HID + c * HID + k] = h;
  Wl[(size_t)l * HID * HID + c * HID + k] = f2bf(w - bf2f(h));
}

// ---------------- generic W split+transpose for MLP weights: [K][C] -> hi/lo [C][K] ----------------
__global__ __launch_bounds__(256) void k_wsplit_t(const float* __restrict__ Win,
                                                  unsigned short* __restrict__ Wth,
                                                  unsigned short* __restrict__ Wtl, int K, int C) {
  int idx = blockIdx.x * 256 + threadIdx.x;
  if (idx < K * C) {
    int k = idx / C, c = idx - k * C;
    float w = Win[idx];
    unsigned short h = f2bf(w);
    Wth[(size_t)c * K + k] = h;
    Wtl[(size_t)c * K + k] = f2bf(w - bf2f(h));
  }
}

// ---------------- aggregation layers 2-4 (prescaled bf16 gather, fp32 accumulate, bf16 A out) ----------------
__global__ __launch_bounds__(256) void k_agg(const unsigned short* __restrict__ xb, const int* __restrict__ row_ptr,
                                             const int* __restrict__ csr_src, const float* __restrict__ norm_dst,
                                             unsigned short* __restrict__ agg_hi) {
  int node = blockIdx.x * 16 + (threadIdx.x >> 4);
  int l16 = threadIdx.x & 15;
  if (node >= N_NODES) return;
  int s0 = row_ptr[node], s1 = row_ptr[node + 1];
  float acc[8];
#pragma unroll
  for (int j = 0; j < 8; ++j) acc[j] = 0.f;
  int i = s0;
  for (; i + 7 < s1; i += 8) {
    uint4 u[8];
#pragma unroll
    for (int e = 0; e < 8; ++e)
      u[e] = *(const uint4*)(xb + (size_t)csr_src[i + e] * HID + l16 * 8);
#pragma unroll
    for (int e = 0; e < 8; ++e) {
      unsigned uu[4] = {u[e].x, u[e].y, u[e].z, u[e].w};
#pragma unroll
      for (int q = 0; q < 4; ++q) {
        union { unsigned u; float f; } lo{uu[q] << 16}, hi{uu[q] & 0xffff0000u};
        acc[q * 2 + 0] += lo.f;
        acc[q * 2 + 1] += hi.f;
      }
    }
  }
  for (; i + 3 < s1; i += 4) {
    uint4 u[4];
#pragma unroll
    for (int e = 0; e < 4; ++e)
      u[e] = *(const uint4*)(xb + (size_t)csr_src[i + e] * HID + l16 * 8);
#pragma unroll
    for (int e = 0; e < 4; ++e) {
      unsigned uu[4] = {u[e].x, u[e].y, u[e].z, u[e].w};
#pragma unroll
      for (int q = 0; q < 4; ++q) {
        union { unsigned u; float f; } lo{uu[q] << 16}, hi{uu[q] & 0xffff0000u};
        acc[q * 2 + 0] += lo.f;
        acc[q * 2 + 1] += hi.f;
      }
    }
  }
  for (; i < s1; ++i) {
    uint4 u = *(const uint4*)(xb + (size_t)csr_src[i] * HID + l16 * 8);
    unsigned uu[4] = {u.x, u.y, u.z, u.w};
#pragma unroll
    for (int q = 0; q < 4; ++q) {
      union { unsigned u; float f; } lo{uu[q] << 16}, hi{uu[q] & 0xffff0000u};
      acc[q * 2 + 0] += lo.f;
      acc[q * 2 + 1] += hi.f;
    }
  }
  float nd = norm_dst[node];
  unsigned short hh[8];
#pragma unroll
  for (int j = 0; j < 8; ++j) hh[j] = f2bf(acc[j] * nd);
  uint4 ho;
  ho.x = (unsigned)hh[0] | ((unsigned)hh[1] << 16); ho.y = (unsigned)hh[2] | ((unsigned)hh[3] << 16);
  ho.z = (unsigned)hh[4] | ((unsigned)hh[5] << 16); ho.w = (unsigned)hh[6] | ((unsigned)hh[7] << 16);
  *(uint4*)(agg_hi + (size_t)node * HID + l16 * 8) = ho;
}

// ---------------- MFMA GEMM: Y = A@W + b; A bf16, W hi/lo (bf16x2); fused BN stats; Yb bf16 ----------------
__global__ __launch_bounds__(256, 4) void k_gemm_mfma(const unsigned short* __restrict__ A,
                                                      const unsigned short* __restrict__ Bh,
                                                      const unsigned short* __restrict__ Bl,
                                                      const float* __restrict__ bias,
                                                      unsigned short* __restrict__ Y16,
                                                      float* __restrict__ sums, float* __restrict__ sumsq) {
  __shared__ unsigned short sA[128 * LSTR], sBh[128 * LSTR], sBl[128 * LSTR];  // 30720 B
  const int tid = threadIdx.x;
  const int lane = tid & 63, wid = tid >> 6;
  const int l15 = lane & 15, kg = lane >> 4;
  const int row0 = blockIdx.x * 128;

  f32x4 acc[2][8];
#pragma unroll
  for (int mi = 0; mi < 2; ++mi)
#pragma unroll
    for (int ni = 0; ni < 8; ++ni) acc[mi][ni] = (f32x4){0.f, 0.f, 0.f, 0.f};

  for (int kb = 0; kb < 4; ++kb) {
    const int k0 = kb * 32;
#pragma unroll
    for (int it = 0; it < 2; ++it) {
      int idx = tid * 2 + it;
      int r = idx >> 2, q = idx & 3;
      int gr = row0 + r;
      s16x8 va = {0, 0, 0, 0, 0, 0, 0, 0};
      if (gr < N_NODES) va = *(const s16x8*)(A + (size_t)gr * HID + k0 + q * 8);
      *(s16x8*)&sA[r * LSTR + q * 8] = va;
      *(s16x8*)&sBh[r * LSTR + q * 8] = *(const s16x8*)(Bh + (size_t)r * HID + k0 + q * 8);
      *(s16x8*)&sBl[r * LSTR + q * 8] = *(const s16x8*)(Bl + (size_t)r * HID + k0 + q * 8);
    }
    __syncthreads();
    s16x8 af[2];
#pragma unroll
    for (int mi = 0; mi < 2; ++mi) {
      int ar = wid * 32 + mi * 16 + l15;
      af[mi] = *(const s16x8*)&sA[ar * LSTR + kg * 8];
    }
#pragma unroll
    for (int ni = 0; ni < 8; ++ni) {
      int bc = ni * 16 + l15;
      s16x8 bh = *(const s16x8*)&sBh[bc * LSTR + kg * 8];
      s16x8 bl = *(const s16x8*)&sBl[bc * LSTR + kg * 8];
#pragma unroll
      for (int mi = 0; mi < 2; ++mi) {
        acc[mi][ni] = __builtin_amdgcn_mfma_f32_16x16x32_bf16(af[mi], bh, acc[mi][ni], 0, 0, 0);
        acc[mi][ni] = __builtin_amdgcn_mfma_f32_16x16x32_bf16(af[mi], bl, acc[mi][ni], 0, 0, 0);
      }
    }
    __syncthreads();
  }

  float bv[8], sp[8], qp[8];
#pragma unroll
  for (int ni = 0; ni < 8; ++ni) {
    bv[ni] = bias[ni * 16 + l15];
    sp[ni] = 0.f; qp[ni] = 0.f;
  }
#pragma unroll
  for (int mi = 0; mi < 2; ++mi) {
    int rbase = row0 + wid * 32 + mi * 16 + kg * 4;
#pragma unroll
    for (int reg = 0; reg < 4; ++reg) {
      int r = rbase + reg;
      if (r < N_NODES) {
        unsigned short* yr = Y16 + (size_t)r * HID;
#pragma unroll
        for (int ni = 0; ni < 8; ++ni) {
          float y = acc[mi][ni][reg] + bv[ni];
          yr[ni * 16 + l15] = f2bf(y);
          sp[ni] += y;
          qp[ni] += y * y;
        }
      }
    }
  }
  __syncthreads();
  float* red_s = (float*)sA;   // [16][128] = 8KB
  float* red_q = (float*)sBh;
  int slot = wid * 4 + kg;
#pragma unroll
  for (int ni = 0; ni < 8; ++ni) {
    red_s[slot * 128 + ni * 16 + l15] = sp[ni];
    red_q[slot * 128 + ni * 16 + l15] = qp[ni];
  }
  __syncthreads();
  if (tid < 128) {
    float a = 0.f, b2 = 0.f;
#pragma unroll
    for (int s = 0; s < 16; ++s) {
      a += red_s[s * 128 + tid];
      b2 += red_q[s * 128 + tid];
    }
    atomicAdd(&sums[tid], a);
    atomicAdd(&sumsq[tid], b2);
  }
}

// ---------------- BN apply + relu + residual (scale/shift derived in-block); writes x + xb ----------------
__global__ __launch_bounds__(256) void k_bn_apply(const unsigned short* __restrict__ Y16,
                                                  const float* __restrict__ sums, const float* __restrict__ sumsq,
                                                  const float* __restrict__ gamma, const float* __restrict__ beta,
                                                  const float* __restrict__ norm_src,
                                                  float* __restrict__ x, unsigned short* __restrict__ xb) {
  __shared__ float scs[128], shs[128];
  int tid = threadIdx.x;
  if (tid < 128) {
    float mu = sums[tid] / (float)N_NODES;
    float var = sumsq[tid] / (float)N_NODES - mu * mu;
    float sc = gamma[tid] * rsqrtf(var + EPSV);
    scs[tid] = sc;
    shs[tid] = beta[tid] - mu * sc;
  }
  __syncthreads();
  int i = blockIdx.x * 256 + tid;  // over N*16 chunks of 8 cols
  const int total = N_NODES * (HID / 8);
  if (i >= total) return;
  int c8 = i & 15, r = i >> 4;
  uint4 yu = *(const uint4*)(Y16 + (size_t)r * HID + c8 * 8);
  unsigned yw[4] = {yu.x, yu.y, yu.z, yu.w};
  float y[8];
#pragma unroll
  for (int q = 0; q < 4; ++q) {
    union { unsigned u; float f; } lo{yw[q] << 16}, hi{yw[q] & 0xffff0000u};
    y[q * 2 + 0] = lo.f;
    y[q * 2 + 1] = hi.f;
  }
  float* xr = x + (size_t)r * HID + c8 * 8;
  float4 x0 = *(const float4*)xr;
  float4 x1 = *(const float4*)(xr + 4);
  float xv[8] = {x0.x, x0.y, x0.z, x0.w, x1.x, x1.y, x1.z, x1.w};
  float o[8];
#pragma unroll
  for (int q = 0; q < 8; ++q)
    o[q] = fmaxf(y[q] * scs[c8 * 8 + q] + shs[c8 * 8 + q], 0.f) + xv[q];
  *(float4*)xr = make_float4(o[0], o[1], o[2], o[3]);
  *(float4*)(xr + 4) = make_float4(o[4], o[5], o[6], o[7]);
  float ns = norm_src[r];
  uint4 p;
  p.x = (unsigned)f2bf(o[0] * ns) | ((unsigned)f2bf(o[1] * ns) << 16);
  p.y = (unsigned)f2bf(o[2] * ns) | ((unsigned)f2bf(o[3] * ns) << 16);
  p.z = (unsigned)f2bf(o[4] * ns) | ((unsigned)f2bf(o[5] * ns) << 16);
  p.w = (unsigned)f2bf(o[6] * ns) | ((unsigned)f2bf(o[7] * ns) << 16);
  *(uint4*)(xb + (size_t)r * HID + c8 * 8) = p;
}

// ---------------- MFMA readout: BN(l=3, in-block) + residual -> 128->64->32->6 ----------------
__global__ __launch_bounds__(256, 4) void k_readout(const unsigned short* __restrict__ Y16,
                                                    const float* __restrict__ Xres,
                                                    const float* __restrict__ sums, const float* __restrict__ sumsq,
                                                    const float* __restrict__ gamma, const float* __restrict__ beta,
                                                    const unsigned short* __restrict__ B1h, const unsigned short* __restrict__ B1l,
                                                    const float* __restrict__ b1,
                                                    const unsigned short* __restrict__ B2h, const unsigned short* __restrict__ B2l,
                                                    const float* __restrict__ b2,
                                                    const float* __restrict__ W3, const float* __restrict__ b3,
                                                    float* __restrict__ out) {
  __shared__ unsigned short sAh[128 * 72], sAl[128 * 72];  // 36864 B
  __shared__ float scs[128], shs[128];
  __shared__ float Ws3s[192];
  const int tid = threadIdx.x;
  const int lane = tid & 63, wid = tid >> 6;
  const int l15 = lane & 15, kg = lane >> 4;
  const int row0 = blockIdx.x * 128;
  if (tid < 128) {
    float mu = sums[tid] / (float)N_NODES;
    float var = sumsq[tid] / (float)N_NODES - mu * mu;
    float sc = gamma[tid] * rsqrtf(var + EPSV);
    scs[tid] = sc;
    shs[tid] = beta[tid] - mu * sc;
  }
  if (tid < 192) Ws3s[tid] = W3[tid];
  __syncthreads();

  f32x4 acc1[2][4];
#pragma unroll
  for (int mi = 0; mi < 2; ++mi)
#pragma unroll
    for (int ni = 0; ni < 4; ++ni) acc1[mi][ni] = (f32x4){0.f, 0.f, 0.f, 0.f};

  for (int slab = 0; slab < 2; ++slab) {
    const int c0 = slab * 64;
#pragma unroll
    for (int it = 0; it < 4; ++it) {
      int idx = tid + it * 256;        // 0..1023
      int r = idx >> 3, q = idx & 7;   // row, 8-col chunk
      int gr = row0 + r;
      float v[8];
      if (gr < N_NODES) {
        uint4 yu = *(const uint4*)(Y16 + (size_t)gr * HID + c0 + q * 8);
        unsigned yw[4] = {yu.x, yu.y, yu.z, yu.w};
        const float* xp = Xres + (size_t)gr * HID + c0 + q * 8;
        float4 x0 = *(const float4*)xp, x1 = *(const float4*)(xp + 4);
        float xvv[8] = {x0.x, x0.y, x0.z, x0.w, x1.x, x1.y, x1.z, x1.w};
        const float* scp = &scs[c0 + q * 8];
        const float* shp = &shs[c0 + q * 8];
#pragma unroll
        for (int qq = 0; qq < 4; ++qq) {
          union { unsigned u; float f; } lo{yw[qq] << 16}, hi{yw[qq] & 0xffff0000u};
          v[qq * 2 + 0] = fmaxf(lo.f * scp[qq * 2 + 0] + shp[qq * 2 + 0], 0.f) + xvv[qq * 2 + 0];
          v[qq * 2 + 1] = fmaxf(hi.f * scp[qq * 2 + 1] + shp[qq * 2 + 1], 0.f) + xvv[qq * 2 + 1];
        }
      } else {
#pragma unroll
        for (int j = 0; j < 8; ++j) v[j] = 0.f;
      }
      short hh[8], ll[8];
#pragma unroll
      for (int j = 0; j < 8; ++j) {
        unsigned short hb = f2bf(v[j]);
        hh[j] = (short)hb;
        ll[j] = (short)f2bf(v[j] - bf2f(hb));
      }
      *(s16x8*)&sAh[r * 72 + q * 8] = (s16x8){hh[0], hh[1], hh[2], hh[3], hh[4], hh[5], hh[6], hh[7]};
      *(s16x8*)&sAl[r * 72 + q * 8] = (s16x8){ll[0], ll[1], ll[2], ll[3], ll[4], ll[5], ll[6], ll[7]};
    }
    __syncthreads();
#pragma unroll
    for (int kb = 0; kb < 2; ++kb) {
      s16x8 afh[2], afl[2];
#pragma unroll
      for (int mi = 0; mi < 2; ++mi) {
        int ar = wid * 32 + mi * 16 + l15;
        afh[mi] = *(const s16x8*)&sAh[ar * 72 + kb * 32 + kg * 8];
        afl[mi] = *(const s16x8*)&sAl[ar * 72 + kb * 32 + kg * 8];
      }
#pragma unroll
      for (int ni = 0; ni < 4; ++ni) {
        int bc = ni * 16 + l15;
        s16x8 bh = *(const s16x8*)(B1h + (size_t)bc * 128 + c0 + kb * 32 + kg * 8);
        s16x8 bl = *(const s16x8*)(B1l + (size_t)bc * 128 + c0 + kb * 32 + kg * 8);
#pragma unroll
        for (int mi = 0; mi < 2; ++mi) {
          acc1[mi][ni] = __builtin_amdgcn_mfma_f32_16x16x32_bf16(afh[mi], bh, acc1[mi][ni], 0, 0, 0);
          acc1[mi][ni] = __builtin_amdgcn_mfma_f32_16x16x32_bf16(afh[mi], bl, acc1[mi][ni], 0, 0, 0);
          acc1[mi][ni] = __builtin_amdgcn_mfma_f32_16x16x32_bf16(afl[mi], bh, acc1[mi][ni], 0, 0, 0);
        }
      }
    }
    __syncthreads();
  }

  float bv1[4];
#pragma unroll
  for (int ni = 0; ni < 4; ++ni) bv1[ni] = b1[ni * 16 + l15];
#pragma unroll
  for (int mi = 0; mi < 2; ++mi)
#pragma unroll
    for (int ni = 0; ni < 4; ++ni)
#pragma unroll
      for (int reg = 0; reg < 4; ++reg) {
        int rr = wid * 32 + mi * 16 + kg * 4 + reg;
        float v = fmaxf(acc1[mi][ni][reg] + bv1[ni], 0.f);
        unsigned short hb = f2bf(v);
        sAh[rr * 72 + ni * 16 + l15] = hb;
        sAl[rr * 72 + ni * 16 + l15] = f2bf(v - bf2f(hb));
      }
  __syncthreads();

  f32x4 acc2[2][2];
#pragma unroll
  for (int mi = 0; mi < 2; ++mi)
#pragma unroll
    for (int ni = 0; ni < 2; ++ni) acc2[mi][ni] = (f32x4){0.f, 0.f, 0.f, 0.f};
#pragma unroll
  for (int kb = 0; kb < 2; ++kb) {
    s16x8 afh[2], afl[2];
#pragma unroll
    for (int mi = 0; mi < 2; ++mi) {
      int ar = wid * 32 + mi * 16 + l15;
      afh[mi] = *(const s16x8*)&sAh[ar * 72 + kb * 32 + kg * 8];
      afl[mi] = *(const s16x8*)&sAl[ar * 72 + kb * 32 + kg * 8];
    }
#pragma unroll
    for (int ni = 0; ni < 2; ++ni) {
      int bc = ni * 16 + l15;
      s16x8 bh = *(const s16x8*)(B2h + (size_t)bc * 64 + kb * 32 + kg * 8);
      s16x8 bl = *(const s16x8*)(B2l + (size_t)bc * 64 + kb * 32 + kg * 8);
#pragma unroll
      for (int mi = 0; mi < 2; ++mi) {
        acc2[mi][ni] = __builtin_amdgcn_mfma_f32_16x16x32_bf16(afh[mi], bh, acc2[mi][ni], 0, 0, 0);
        acc2[mi][ni] = __builtin_amdgcn_mfma_f32_16x16x32_bf16(afh[mi], bl, acc2[mi][ni], 0, 0, 0);
        acc2[mi][ni] = __builtin_amdgcn_mfma_f32_16x16x32_bf16(afl[mi], bh, acc2[mi][ni], 0, 0, 0);
      }
    }
  }
  __syncthreads();

  float* h2s = (float*)sAh;
  float bv2[2];
#pragma unroll
  for (int ni = 0; ni < 2; ++ni) bv2[ni] = b2[ni * 16 + l15];
#pragma unroll
  for (int mi = 0; mi < 2; ++mi)
#pragma unroll
    for (int ni = 0; ni < 2; ++ni)
#pragma unroll
      for (int reg = 0; reg < 4; ++reg) {
        int rr = wid * 32 + mi * 16 + kg * 4 + reg;
        h2s[rr * 36 + ni * 16 + l15] = fmaxf(acc2[mi][ni][reg] + bv2[ni], 0.f);
      }
  __syncthreads();

  if (tid < 128) {
    int gr = row0 + tid;
    if (gr < N_NODES) {
      float h2r[32];
#pragma unroll
      for (int q = 0; q < 8; ++q) {
        float4 t = *(const float4*)&h2s[tid * 36 + q * 4];
        h2r[q * 4 + 0] = t.x; h2r[q * 4 + 1] = t.y; h2r[q * 4 + 2] = t.z; h2r[q * 4 + 3] = t.w;
      }
      float p[6];
#pragma unroll
      for (int o = 0; o < 6; ++o) p[o] = b3[o];
#pragma unroll
      for (int k = 0; k < 32; ++k)
#pragma unroll
        for (int o = 0; o < 6; ++o) p[o] += h2r[k] * Ws3s[k * 6 + o];
      float* orow = out + (size_t)gr * 6;
#pragma unroll
      for (int o = 0; o < 6; ++o) orow[o] = p[o];
    }
  }
}

extern "C" void kernel_launch(void* const* d_in, const int* in_sizes, int n_in,
                              void* d_out, int out_size, void* d_ws, size_t ws_size,
                              hipStream_t stream) {
  const int* h = (const int*)d_in[0];
  const int* src = (const int*)d_in[1];
  const int* dst = (const int*)d_in[2];
  const float* emb = (const float*)d_in[3];
  const float* W = (const float*)d_in[4];
  const float* b = (const float*)d_in[5];
  const float* gamma = (const float*)d_in[6];
  const float* beta = (const float*)d_in[7];
  const float* W1 = (const float*)d_in[8];
  const float* b1 = (const float*)d_in[9];
  const float* W2 = (const float*)d_in[10];
  const float* b2 = (const float*)d_in[11];
  const float* W3 = (const float*)d_in[12];
  const float* b3 = (const float*)d_in[13];
  float* out = (float*)d_out;

  char* ws = (char*)d_ws;
  size_t off = 0;
  auto alloc = [&](size_t bytes) -> void* {
    void* p = ws + off;
    off += (bytes + 255) & ~(size_t)255;
    return p;
  };
  float* norm_src = (float*)alloc(N_NODES * 4);
  float* norm_dst = (float*)alloc(N_NODES * 4);
  int* row_ptr = (int*)alloc((N_NODES + 1) * 4);
  int* csr_src = (int*)alloc((size_t)N_EDGES * 4);
  int* bucket_cnt_d = (int*)alloc(NBUCK * 4);
  int* bucket_base_d = (int*)alloc((NBUCK + 1) * 4);
  int* bucket_fill_d = (int*)alloc(NBUCK * 4);
  int* bucket_cnt_s = (int*)alloc(NBUCK * 4);
  int* bucket_base_s = (int*)alloc((NBUCK + 1) * 4);
  int* bucket_fill_s = (int*)alloc(NBUCK * 4);
  float* x = (float*)alloc((size_t)N_NODES * HID * 4);
  unsigned short* xb = (unsigned short*)alloc((size_t)N_NODES * HID * 2);
  unsigned short* agg_hi = (unsigned short*)alloc((size_t)N_NODES * HID * 2);
  unsigned short* Yb16 = (unsigned short*)alloc((size_t)N_NODES * HID * 2);
  unsigned short* Wh = (unsigned short*)alloc((size_t)N_LAYERS * HID * HID * 2);
  unsigned short* Wl = (unsigned short*)alloc((size_t)N_LAYERS * HID * HID * 2);
  unsigned short* B1h = (unsigned short*)alloc(64 * 128 * 2);
  unsigned short* B1l = (unsigned short*)alloc(64 * 128 * 2);
  unsigned short* B2h = (unsigned short*)alloc(32 * 64 * 2);
  unsigned short* B2l = (unsigned short*)alloc(32 * 64 * 2);
  float* sums = (float*)alloc(512);
  float* sumsq = (float*)alloc(512);
  int2* pairs = (int2*)alloc((size_t)N_EDGES * 8);  // 12.8MB
  int* svals = (int*)alloc((size_t)N_EDGES * 4);    // 6.4MB

  hipMemsetAsync(bucket_cnt_d, 0, NBUCK * 4, stream);
  hipMemsetAsync(bucket_cnt_s, 0, NBUCK * 4, stream);
  k_hist2<<<1024, 256, 0, stream>>>(src, dst, bucket_cnt_d, bucket_cnt_s);
  k_bscan<<<1, 256, 0, stream>>>(bucket_cnt_d, bucket_base_d, bucket_fill_d);
  k_bscan<<<1, 256, 0, stream>>>(bucket_cnt_s, bucket_base_s, bucket_fill_s);
  k_scatter2<<<(N_EDGES + CBLK - 1) / CBLK, 256, 0, stream>>>(src, dst, bucket_base_d, bucket_fill_d, pairs);
  k_scatter_src<<<(N_EDGES + CBLK - 1) / CBLK, 256, 0, stream>>>(src, bucket_base_s, bucket_fill_s, svals);
  k_bucket_csr<<<NBUCK, 256, 0, stream>>>(pairs, bucket_base_d, row_ptr, norm_dst, csr_src);
  k_src_count<<<NBUCK, 256, 0, stream>>>(svals, bucket_base_s, norm_src);
  k_embed<<<(N_NODES * (HID / 4) + 255) / 256, 256, 0, stream>>>(h, emb, x);
  k_wsplit<<<N_LAYERS * 128, 128, 0, stream>>>(W, Wh, Wl);
  k_wsplit_t<<<(128 * 64 + 255) / 256, 256, 0, stream>>>(W1, B1h, B1l, 128, 64);
  k_wsplit_t<<<(64 * 32 + 255) / 256, 256, 0, stream>>>(W2, B2h, B2l, 64, 32);

  for (int l = 0; l < N_LAYERS; ++l) {
    if (l == 0) {
      k_agg1<<<(N_NODES + 63) / 64, 256, 0, stream>>>(row_ptr, csr_src, h, norm_src, norm_dst, emb, agg_hi);
    } else {
      k_agg<<<(N_NODES + 15) / 16, 256, 0, stream>>>(xb, row_ptr, csr_src, norm_dst, agg_hi);
    }
    hipMemsetAsync(sums, 0, 1024, stream);  // sums+sumsq contiguous
    k_gemm_mfma<<<(N_NODES + 127) / 128, 256, 0, stream>>>(agg_hi,
                                                           Wh + (size_t)l * HID * HID, Wl + (size_t)l * HID * HID,
                                                           b + l * HID, Yb16, sums, sumsq);
    if (l < N_LAYERS - 1) {
      k_bn_apply<<<(N_NODES * (HID / 8) + 255) / 256, 256, 0, stream>>>(Yb16, sums, sumsq,
                                                                        gamma + l * HID, beta + l * HID,
                                                                        norm_src, x, xb);
    }
  }
  k_readout<<<(N_NODES + 127) / 128, 256, 0, stream>>>(Yb16, x, sums, sumsq,
                                                       gamma + 3 * HID, beta + 3 * HID,
                                                       B1h, B1l, b1, B2h, B2l, b2, W3, b3, out);
}